// Round 2
// baseline (1740.330 us; speedup 1.0000x reference)
//
#include <hip/hip_runtime.h>
#include <math.h>

#define NN 10000     // nodes
#define NE 160000    // edges
#define CC 72        // channels
#define AA 16        // node attr dim
#define LL 3         // layers
#define OO 64        // out dim
#define NBATCH 16
#define SH 9
#define FCN 100
#define KK (SH*CC)   // 648
#define NCH 9        // K-chunks in split-K
#define BK 72        // chunk K size
#define PSTRIDE 12   // padded per-edge path stride (float4-aligned)

// ---------------------------------------------------------------- helpers
static __device__ __forceinline__ float gelu_tanh(float x) {
    float x3 = x * x * x;
    float inner = 0.7978845608028654f * (x + 0.044715f * x3);
    return 0.5f * x * (1.0f + tanhf(inner));
}

// ---------------------------------------------------------------- 1) histogram of kept edges per dst
__global__ void k_hist(const float* __restrict__ pos, const int* __restrict__ esrc,
                       const int* __restrict__ edst, int* __restrict__ cnt) {
    int e = blockIdx.x * blockDim.x + threadIdx.x;
    if (e >= NE) return;
    int s = esrc[e], d = edst[e];
    float dx = pos[3 * s] - pos[3 * d];
    float dy = pos[3 * s + 1] - pos[3 * d + 1];
    float dz = pos[3 * s + 2] - pos[3 * d + 2];
    float r = sqrtf(dx * dx + dy * dy + dz * dz);
    // t = r/2 >= 1 -> emb==0 -> silu(0)=0 (fc1_b==0) -> path==0: drop edge.
    if (r * 0.5f < 1.0f) atomicAdd(&cnt[d], 1);
}

// ---------------------------------------------------------------- 2) exclusive scan -> off[0..NN]
__global__ void k_scan(const int* __restrict__ cnt, int* __restrict__ off) {
    __shared__ int sa[256], sb[256];
    const int PER = 40; // 256*40 >= NN+1
    int t = threadIdx.x;
    int base = t * PER;
    int loc[PER];
    int run = 0;
#pragma unroll
    for (int i = 0; i < PER; ++i) {
        int idx = base + i;
        int v = (idx < NN) ? cnt[idx] : 0;
        loc[i] = run;
        run += v;
    }
    sa[t] = run;
    __syncthreads();
    int* in = sa; int* out = sb;
    for (int o = 1; o < 256; o <<= 1) {
        int v = in[t];
        if (t >= o) v += in[t - o];
        out[t] = v;
        __syncthreads();
        int* tmp = in; in = out; out = tmp;
    }
    int ebase = (t > 0) ? in[t - 1] : 0;
#pragma unroll
    for (int i = 0; i < PER; ++i) {
        int idx = base + i;
        if (idx <= NN) off[idx] = ebase + loc[i];
    }
}

// ---------------------------------------------------------------- 3) scatter kept edges dst-sorted
__global__ void k_scatter(const float* __restrict__ pos, const int* __restrict__ esrc,
                          const int* __restrict__ edst, const int* __restrict__ off,
                          int* __restrict__ cur, int* __restrict__ src_s) {
    int e = blockIdx.x * blockDim.x + threadIdx.x;
    if (e >= NE) return;
    int s = esrc[e], d = edst[e];
    float dx = pos[3 * s] - pos[3 * d];
    float dy = pos[3 * s + 1] - pos[3 * d + 1];
    float dz = pos[3 * s + 2] - pos[3 * d + 2];
    float r = sqrtf(dx * dx + dy * dy + dz * dz);
    if (r * 0.5f < 1.0f) {
        int slot = off[d] + atomicAdd(&cur[d], 1);
        src_s[slot] = s;
        // store the geometry alongside to avoid re-deriving in k_path:
        // (kept simple: k_path recomputes from pos via src/dst) -- we store dst too
    }
}

// separate dst store kept out: k_path needs dst; recompute via second scatter arg
__global__ void k_scatter2(const float* __restrict__ pos, const int* __restrict__ esrc,
                           const int* __restrict__ edst, const int* __restrict__ off,
                           int* __restrict__ cur, int* __restrict__ src_s,
                           int* __restrict__ dst_s) {
    int e = blockIdx.x * blockDim.x + threadIdx.x;
    if (e >= NE) return;
    int s = esrc[e], d = edst[e];
    float dx = pos[3 * s] - pos[3 * d];
    float dy = pos[3 * s + 1] - pos[3 * d + 1];
    float dz = pos[3 * s + 2] - pos[3 * d + 2];
    float r = sqrtf(dx * dx + dy * dy + dz * dz);
    if (r * 0.5f < 1.0f) {
        int slot = off[d] + atomicAdd(&cur[d], 1);
        src_s[slot] = s;
        dst_s[slot] = d;
    }
}

// ---------------------------------------------------------------- 4) per-edge path[l][slot][12] (padded)
__global__ __launch_bounds__(256) void k_path(const float* __restrict__ pos,
                                              const int* __restrict__ src_s,
                                              const int* __restrict__ dst_s,
                                              const float* __restrict__ fc1w,
                                              const float* __restrict__ fc1b,
                                              const float* __restrict__ fc2w,
                                              const int* __restrict__ off,
                                              float* __restrict__ path) {
    __shared__ float w1[LL * FCN], b1[LL * FCN], w2[LL * FCN * SH];
    for (int i = threadIdx.x; i < LL * FCN; i += blockDim.x) { w1[i] = fc1w[i]; b1[i] = fc1b[i]; }
    for (int i = threadIdx.x; i < LL * FCN * SH; i += blockDim.x) w2[i] = fc2w[i];
    __syncthreads();
    int slot = blockIdx.x * blockDim.x + threadIdx.x;
    int total = off[NN];
    if (slot >= total) return;
    int s = src_s[slot], d = dst_s[slot];
    float dx = pos[3 * s] - pos[3 * d];
    float dy = pos[3 * s + 1] - pos[3 * d + 1];
    float dz = pos[3 * s + 2] - pos[3 * d + 2];
    float r = sqrtf(dx * dx + dy * dy + dz * dz);
    float inv = 1.0f / fmaxf(r, 1e-9f);
    float x = dx * inv, y = dy * inv, z = dz * inv;
    const float s3 = 1.7320508075688772f;
    const float s5 = 2.23606797749979f;
    const float s15 = 3.872983346207417f;
    float sh[SH];
    sh[0] = 1.0f;
    sh[1] = s3 * x;
    sh[2] = s3 * y;
    sh[3] = s3 * z;
    sh[4] = s15 * x * y;
    sh[5] = s15 * y * z;
    sh[6] = 0.5f * s5 * (3.0f * z * z - 1.0f);
    sh[7] = s15 * x * z;
    sh[8] = 0.5f * s15 * (x * x - y * y);
    float t = r * 0.5f;
    float emb = cosf(1.5707963267948966f * t);

    for (int l = 0; l < LL; ++l) {
        float u[SH];
#pragma unroll
        for (int q = 0; q < SH; ++q) u[q] = 0.f;
        const float* lw1 = &w1[l * FCN];
        const float* lb1 = &b1[l * FCN];
        const float* lw2 = &w2[l * FCN * SH];
        for (int f = 0; f < FCN; ++f) {
            float a = emb * lw1[f] + lb1[f];
            float si = a / (1.0f + expf(-a));
#pragma unroll
            for (int q = 0; q < SH; ++q) u[q] += si * lw2[f * SH + q];
        }
        float* pd = &path[((size_t)l * NE + slot) * PSTRIDE];
#pragma unroll
        for (int q = 0; q < SH; ++q) pd[q] = u[q] * sh[q];
        pd[9] = 0.f; pd[10] = 0.f; pd[11] = 0.f;
    }
}

// ---------------------------------------------------------------- 5) h init
__global__ void k_init(const float* __restrict__ W_in, float* __restrict__ h) {
    int i = blockIdx.x * blockDim.x + threadIdx.x;
    if (i < NN * CC) h[i] = W_in[i % CC];
}

// ---------------------------------------------------------------- 6) Z: wave per node
__global__ __launch_bounds__(256) void k_z2(const float* __restrict__ h,
                                            const float* __restrict__ path_l,
                                            const int* __restrict__ src_s,
                                            const int* __restrict__ off,
                                            float* __restrict__ Z) {
    int d = blockIdx.x * 4 + (threadIdx.x >> 6);
    int lane = threadIdx.x & 63;
    if (d >= NN) return;
    float a1[SH], a2[SH];
#pragma unroll
    for (int q = 0; q < SH; ++q) { a1[q] = 0.f; a2[q] = 0.f; }
    int b = off[d], e = off[d + 1];
    bool two = lane < (CC - 64); // 8 lanes handle a second channel
    for (int i = b; i < e; ++i) {
        int s = src_s[i];
        float hv1 = h[(size_t)s * CC + lane];
        float hv2 = two ? h[(size_t)s * CC + 64 + lane] : 0.f;
        const float* p = &path_l[(size_t)i * PSTRIDE];
        float4 p0 = *(const float4*)p;
        float4 p1 = *(const float4*)(p + 4);
        float p8 = p[8];
        a1[0] += p0.x * hv1; a2[0] += p0.x * hv2;
        a1[1] += p0.y * hv1; a2[1] += p0.y * hv2;
        a1[2] += p0.z * hv1; a2[2] += p0.z * hv2;
        a1[3] += p0.w * hv1; a2[3] += p0.w * hv2;
        a1[4] += p1.x * hv1; a2[4] += p1.x * hv2;
        a1[5] += p1.y * hv1; a2[5] += p1.y * hv2;
        a1[6] += p1.z * hv1; a2[6] += p1.z * hv2;
        a1[7] += p1.w * hv1; a2[7] += p1.w * hv2;
        a1[8] += p8 * hv1;   a2[8] += p8 * hv2;
    }
    float* zd = &Z[(size_t)d * KK];
#pragma unroll
    for (int q = 0; q < SH; ++q) {
        zd[q * CC + lane] = a1[q];
        if (two) zd[q * CC + 64 + lane] = a2[q];
    }
}

// ---------------------------------------------------------------- 7a) split-K TP GEMM: partial[kc] = Z_chunk @ W_chunk
__global__ __launch_bounds__(288) void k_tp(const float* __restrict__ Z,
                                            const float* __restrict__ Wtp,
                                            float* __restrict__ partial) {
    __shared__ float Zs[32][80];
    __shared__ float Ws[BK][CC];
    int kc = blockIdx.y;
    int n0 = blockIdx.x * 32;
    int t = threadIdx.x;
    int cp = t % 72, y = t / 72;

    for (int i = t; i < BK * CC; i += 288)
        ((float*)Ws)[i] = Wtp[(size_t)kc * BK * CC + i];
    {
        int row = t / 9, j = t % 9;
        int n = n0 + row;
        int nc = (n < NN) ? n : (NN - 1);
        const float* src = &Z[(size_t)nc * KK + kc * BK + 8 * j];
        float4 a = *(const float4*)src;
        float4 b = *(const float4*)(src + 4);
        *(float4*)&Zs[row][8 * j] = a;
        *(float4*)&Zs[row][8 * j + 4] = b;
    }
    __syncthreads();

    float acc[8];
#pragma unroll
    for (int rr = 0; rr < 8; ++rr) acc[rr] = 0.f;

#pragma unroll
    for (int kk = 0; kk < 18; ++kk) {
        float w0 = Ws[4 * kk + 0][cp];
        float w1 = Ws[4 * kk + 1][cp];
        float w2 = Ws[4 * kk + 2][cp];
        float w3 = Ws[4 * kk + 3][cp];
#pragma unroll
        for (int rr = 0; rr < 8; ++rr) {
            int r = y + 4 * rr;
            float4 z = *(const float4*)&Zs[r][4 * kk];
            acc[rr] += z.x * w0 + z.y * w1 + z.z * w2 + z.w * w3;
        }
    }
    float* pb = &partial[(size_t)kc * NN * CC];
#pragma unroll
    for (int rr = 0; rr < 8; ++rr) {
        int n = n0 + y + 4 * rr;
        if (n < NN) pb[(size_t)n * CC + cp] = acc[rr];
    }
}

// ---------------------------------------------------------------- 7b) reduce partials + self + attr + gelu
__global__ __launch_bounds__(288) void k_fin(const float* __restrict__ partial,
                                             const float* __restrict__ hin,
                                             const float* __restrict__ attr,
                                             const float* __restrict__ Wself,
                                             const float* __restrict__ Wattr,
                                             float* __restrict__ hout) {
    __shared__ float Hs[16][80];
    __shared__ float Ws[CC][CC];
    __shared__ float Wa[AA][CC];
    __shared__ float As[16][20];
    int n0 = blockIdx.x * 16;
    int t = threadIdx.x;
    int cp = t % 72, y = t / 72;

    for (int i = t; i < CC * CC; i += 288) ((float*)Ws)[i] = Wself[i];
    for (int i = t; i < AA * CC; i += 288) ((float*)Wa)[i] = Wattr[i];
    {
        int row = t / 18, j = t % 18; // 16 rows x 18 threads, 4 floats each
        int nc = min(n0 + row, NN - 1);
        *(float4*)&Hs[row][4 * j] = *(const float4*)&hin[(size_t)nc * CC + 4 * j];
    }
    if (t < 256) {
        int row = t / 16, a = t % 16;
        int nc = min(n0 + row, NN - 1);
        As[row][a] = attr[(size_t)nc * AA + a];
    }
    __syncthreads();

    float acc[4] = {0.f, 0.f, 0.f, 0.f};
#pragma unroll
    for (int kk = 0; kk < 18; ++kk) {
        float w0 = Ws[4 * kk + 0][cp];
        float w1 = Ws[4 * kk + 1][cp];
        float w2 = Ws[4 * kk + 2][cp];
        float w3 = Ws[4 * kk + 3][cp];
#pragma unroll
        for (int rr = 0; rr < 4; ++rr) {
            int r = y + 4 * rr;
            float4 h4 = *(const float4*)&Hs[r][4 * kk];
            acc[rr] += h4.x * w0 + h4.y * w1 + h4.z * w2 + h4.w * w3;
        }
    }
#pragma unroll
    for (int kk = 0; kk < 4; ++kk) {
        float w0 = Wa[4 * kk + 0][cp];
        float w1 = Wa[4 * kk + 1][cp];
        float w2 = Wa[4 * kk + 2][cp];
        float w3 = Wa[4 * kk + 3][cp];
#pragma unroll
        for (int rr = 0; rr < 4; ++rr) {
            int r = y + 4 * rr;
            float4 a4 = *(const float4*)&As[r][4 * kk];
            acc[rr] += a4.x * w0 + a4.y * w1 + a4.z * w2 + a4.w * w3;
        }
    }
#pragma unroll
    for (int rr = 0; rr < 4; ++rr) {
        int n = n0 + y + 4 * rr;
        if (n < NN) {
            float s = 0.f;
#pragma unroll
            for (int kc = 0; kc < NCH; ++kc)
                s += partial[(size_t)kc * NN * CC + (size_t)n * CC + cp];
            hout[(size_t)n * CC + cp] = gelu_tanh(acc[rr] + 0.25f * s);
        }
    }
}

// ---------------------------------------------------------------- 8) out = segpool(h@W_out)/25
__global__ __launch_bounds__(256) void k_out(const float* __restrict__ h,
                                             const float* __restrict__ Wout,
                                             const int* __restrict__ batch,
                                             float* __restrict__ out) {
    __shared__ float sp[NBATCH * OO];
    int tid = threadIdx.x;
    for (int i = tid; i < NBATCH * OO; i += blockDim.x) sp[i] = 0.f;
    __syncthreads();
    int wave = tid >> 6, lane = tid & 63;
    const int WPB = 4;
    for (int n = blockIdx.x * WPB + wave; n < NN; n += gridDim.x * WPB) {
        const float* hr = &h[(size_t)n * CC];
        float acc = 0.f;
#pragma unroll 8
        for (int c = 0; c < CC; ++c) acc += hr[c] * Wout[c * OO + lane];
        atomicAdd(&sp[batch[n] * OO + lane], acc * (1.0f / 25.0f));
    }
    __syncthreads();
    for (int i = tid; i < NBATCH * OO; i += blockDim.x) {
        float v = sp[i];
        if (v != 0.f) atomicAdd(&out[i], v);
    }
}

// ---------------------------------------------------------------- launch
extern "C" void kernel_launch(void* const* d_in, const int* in_sizes, int n_in,
                              void* d_out, int out_size, void* d_ws, size_t ws_size,
                              hipStream_t stream) {
    const float* pos       = (const float*)d_in[0];
    const float* node_attr = (const float*)d_in[1];
    const int*   batch     = (const int*)d_in[2];
    const int*   esrc      = (const int*)d_in[3];
    const int*   edst      = (const int*)d_in[4];
    const float* W_in      = (const float*)d_in[5];
    const float* W_tp      = (const float*)d_in[6];
    const float* W_self    = (const float*)d_in[7];
    const float* W_attr    = (const float*)d_in[8];
    const float* fc1w      = (const float*)d_in[9];
    const float* fc1b      = (const float*)d_in[10];
    const float* fc2w      = (const float*)d_in[11];
    const float* W_out     = (const float*)d_in[12];
    float* out = (float*)d_out;

    char* p = (char*)d_ws;
    auto alloc = [&](size_t bytes) -> void* {
        void* r = (void*)p;
        p += (bytes + 255) & ~(size_t)255;
        return r;
    };
    int*   cnt     = (int*)alloc((size_t)NN * 4);
    int*   cur     = (int*)alloc((size_t)NN * 4);
    int*   off     = (int*)alloc((size_t)(NN + 1) * 4);
    int*   src_s   = (int*)alloc((size_t)NE * 4);
    int*   dst_s   = (int*)alloc((size_t)NE * 4);
    float* path    = (float*)alloc((size_t)LL * NE * PSTRIDE * 4);
    float* Z       = (float*)alloc((size_t)NN * KK * 4);
    float* partial = (float*)alloc((size_t)NCH * NN * CC * 4);
    float* h0      = (float*)alloc((size_t)NN * CC * 4);
    float* h1      = (float*)alloc((size_t)NN * CC * 4);

    hipMemsetAsync(cnt, 0, (size_t)NN * 4, stream);
    hipMemsetAsync(cur, 0, (size_t)NN * 4, stream);
    hipMemsetAsync(out, 0, (size_t)NBATCH * OO * 4, stream);

    k_hist<<<(NE + 255) / 256, 256, 0, stream>>>(pos, esrc, edst, cnt);
    k_scan<<<1, 256, 0, stream>>>(cnt, off);
    k_scatter2<<<(NE + 255) / 256, 256, 0, stream>>>(pos, esrc, edst, off, cur, src_s, dst_s);
    k_path<<<(NE + 255) / 256, 256, 0, stream>>>(pos, src_s, dst_s, fc1w, fc1b, fc2w, off, path);
    k_init<<<(NN * CC + 255) / 256, 256, 0, stream>>>(W_in, h0);

    const float* hin = h0;
    float* hout = h1;
    for (int l = 0; l < LL; ++l) {
        k_z2<<<(NN + 3) / 4, 256, 0, stream>>>(hin, path + (size_t)l * NE * PSTRIDE, src_s, off, Z);
        k_tp<<<dim3((NN + 31) / 32, NCH), 288, 0, stream>>>(
            Z, W_tp + (size_t)l * KK * CC, partial);
        k_fin<<<(NN + 15) / 16, 288, 0, stream>>>(
            partial, hin, node_attr,
            W_self + (size_t)l * CC * CC,
            W_attr + (size_t)l * AA * CC,
            hout);
        const float* tmp = hin; hin = hout; hout = (float*)tmp;
    }
    k_out<<<128, 256, 0, stream>>>(hin, W_out, batch, out);
}

// Round 3
// 562.928 us; speedup vs baseline: 3.0916x; 3.0916x over previous
//
#include <hip/hip_runtime.h>
#include <math.h>

#define NN 10000     // nodes
#define NE 160000    // edges
#define CC 72        // channels
#define AA 16        // node attr dim
#define LL 3         // layers
#define OO 64        // out dim
#define NBATCH 16
#define SH 9
#define FCN 100
#define KK (SH*CC)   // 648
#define PSTRIDE 12   // padded per-edge path stride (float4-aligned)
#define TROW 16      // nodes per k_agg2 block
#define LW 740       // LDS row: 648 Z + 72 h + 16 attr + 4 pad (float4-aligned)

// ---------------------------------------------------------------- helpers
static __device__ __forceinline__ float gelu_tanh(float x) {
    float x3 = x * x * x;
    float inner = 0.7978845608028654f * (x + 0.044715f * x3);
    return 0.5f * x * (1.0f + tanhf(inner));
}

// ---------------------------------------------------------------- 1) histogram of kept edges per dst
__global__ void k_hist(const float* __restrict__ pos, const int* __restrict__ esrc,
                       const int* __restrict__ edst, int* __restrict__ cnt) {
    int e = blockIdx.x * blockDim.x + threadIdx.x;
    if (e >= NE) return;
    int s = esrc[e], d = edst[e];
    float dx = pos[3 * s] - pos[3 * d];
    float dy = pos[3 * s + 1] - pos[3 * d + 1];
    float dz = pos[3 * s + 2] - pos[3 * d + 2];
    float r = sqrtf(dx * dx + dy * dy + dz * dz);
    // t = r/2 >= 1 -> emb==0 -> silu(0)=0 (fc1_b==0) -> path==0: drop edge.
    if (r * 0.5f < 1.0f) atomicAdd(&cnt[d], 1);
}

// ---------------------------------------------------------------- 2) exclusive scan -> off[0..NN]
__global__ void k_scan(const int* __restrict__ cnt, int* __restrict__ off) {
    __shared__ int sa[256], sb[256];
    const int PER = 40; // 256*40 >= NN+1
    int t = threadIdx.x;
    int base = t * PER;
    int loc[PER];
    int run = 0;
#pragma unroll
    for (int i = 0; i < PER; ++i) {
        int idx = base + i;
        int v = (idx < NN) ? cnt[idx] : 0;
        loc[i] = run;
        run += v;
    }
    sa[t] = run;
    __syncthreads();
    int* in = sa; int* out = sb;
    for (int o = 1; o < 256; o <<= 1) {
        int v = in[t];
        if (t >= o) v += in[t - o];
        out[t] = v;
        __syncthreads();
        int* tmp = in; in = out; out = tmp;
    }
    int ebase = (t > 0) ? in[t - 1] : 0;
#pragma unroll
    for (int i = 0; i < PER; ++i) {
        int idx = base + i;
        if (idx <= NN) off[idx] = ebase + loc[i];
    }
}

// ---------------------------------------------------------------- 3) scatter kept edges dst-sorted
__global__ void k_scatter2(const float* __restrict__ pos, const int* __restrict__ esrc,
                           const int* __restrict__ edst, const int* __restrict__ off,
                           int* __restrict__ cur, int* __restrict__ src_s,
                           int* __restrict__ dst_s) {
    int e = blockIdx.x * blockDim.x + threadIdx.x;
    if (e >= NE) return;
    int s = esrc[e], d = edst[e];
    float dx = pos[3 * s] - pos[3 * d];
    float dy = pos[3 * s + 1] - pos[3 * d + 1];
    float dz = pos[3 * s + 2] - pos[3 * d + 2];
    float r = sqrtf(dx * dx + dy * dy + dz * dz);
    if (r * 0.5f < 1.0f) {
        int slot = off[d] + atomicAdd(&cur[d], 1);
        src_s[slot] = s;
        dst_s[slot] = d;
    }
}

// ---------------------------------------------------------------- 4) per-edge path[l][slot][12] (padded)
__global__ __launch_bounds__(256) void k_path(const float* __restrict__ pos,
                                              const int* __restrict__ src_s,
                                              const int* __restrict__ dst_s,
                                              const float* __restrict__ fc1w,
                                              const float* __restrict__ fc1b,
                                              const float* __restrict__ fc2w,
                                              const int* __restrict__ off,
                                              float* __restrict__ path) {
    __shared__ float w1[LL * FCN], b1[LL * FCN], w2[LL * FCN * SH];
    for (int i = threadIdx.x; i < LL * FCN; i += blockDim.x) { w1[i] = fc1w[i]; b1[i] = fc1b[i]; }
    for (int i = threadIdx.x; i < LL * FCN * SH; i += blockDim.x) w2[i] = fc2w[i];
    __syncthreads();
    int slot = blockIdx.x * blockDim.x + threadIdx.x;
    int total = off[NN];
    if (slot >= total) return;
    int s = src_s[slot], d = dst_s[slot];
    float dx = pos[3 * s] - pos[3 * d];
    float dy = pos[3 * s + 1] - pos[3 * d + 1];
    float dz = pos[3 * s + 2] - pos[3 * d + 2];
    float r = sqrtf(dx * dx + dy * dy + dz * dz);
    float inv = 1.0f / fmaxf(r, 1e-9f);
    float x = dx * inv, y = dy * inv, z = dz * inv;
    const float s3 = 1.7320508075688772f;
    const float s5 = 2.23606797749979f;
    const float s15 = 3.872983346207417f;
    float sh[SH];
    sh[0] = 1.0f;
    sh[1] = s3 * x;
    sh[2] = s3 * y;
    sh[3] = s3 * z;
    sh[4] = s15 * x * y;
    sh[5] = s15 * y * z;
    sh[6] = 0.5f * s5 * (3.0f * z * z - 1.0f);
    sh[7] = s15 * x * z;
    sh[8] = 0.5f * s15 * (x * x - y * y);
    float t = r * 0.5f;
    float emb = cosf(1.5707963267948966f * t);

    for (int l = 0; l < LL; ++l) {
        float u[SH];
#pragma unroll
        for (int q = 0; q < SH; ++q) u[q] = 0.f;
        const float* lw1 = &w1[l * FCN];
        const float* lb1 = &b1[l * FCN];
        const float* lw2 = &w2[l * FCN * SH];
        for (int f = 0; f < FCN; ++f) {
            float a = emb * lw1[f] + lb1[f];
            float si = a / (1.0f + expf(-a));
#pragma unroll
            for (int q = 0; q < SH; ++q) u[q] += si * lw2[f * SH + q];
        }
        float* pd = &path[((size_t)l * NE + slot) * PSTRIDE];
#pragma unroll
        for (int q = 0; q < SH; ++q) pd[q] = u[q] * sh[q];
        pd[9] = 0.f; pd[10] = 0.f; pd[11] = 0.f;
    }
}

// ---------------------------------------------------------------- 5) h init
__global__ void k_init(const float* __restrict__ W_in, float* __restrict__ h) {
    int i = blockIdx.x * blockDim.x + threadIdx.x;
    if (i < NN * CC) h[i] = W_in[i % CC];
}

// ---------------------------------------------------------------- 6) Z: wave per node
__global__ __launch_bounds__(256) void k_z2(const float* __restrict__ h,
                                            const float* __restrict__ path_l,
                                            const int* __restrict__ src_s,
                                            const int* __restrict__ off,
                                            float* __restrict__ Z) {
    int d = blockIdx.x * 4 + (threadIdx.x >> 6);
    int lane = threadIdx.x & 63;
    if (d >= NN) return;
    float a1[SH], a2[SH];
#pragma unroll
    for (int q = 0; q < SH; ++q) { a1[q] = 0.f; a2[q] = 0.f; }
    int b = off[d], e = off[d + 1];
    bool two = lane < (CC - 64); // 8 lanes handle a second channel
    for (int i = b; i < e; ++i) {
        int s = src_s[i];
        float hv1 = h[(size_t)s * CC + lane];
        float hv2 = two ? h[(size_t)s * CC + 64 + lane] : 0.f;
        const float* p = &path_l[(size_t)i * PSTRIDE];
        float4 p0 = *(const float4*)p;
        float4 p1 = *(const float4*)(p + 4);
        float p8 = p[8];
        a1[0] += p0.x * hv1; a2[0] += p0.x * hv2;
        a1[1] += p0.y * hv1; a2[1] += p0.y * hv2;
        a1[2] += p0.z * hv1; a2[2] += p0.z * hv2;
        a1[3] += p0.w * hv1; a2[3] += p0.w * hv2;
        a1[4] += p1.x * hv1; a2[4] += p1.x * hv2;
        a1[5] += p1.y * hv1; a2[5] += p1.y * hv2;
        a1[6] += p1.z * hv1; a2[6] += p1.z * hv2;
        a1[7] += p1.w * hv1; a2[7] += p1.w * hv2;
        a1[8] += p8 * hv1;   a2[8] += p8 * hv2;
    }
    float* zd = &Z[(size_t)d * KK];
#pragma unroll
    for (int q = 0; q < SH; ++q) {
        zd[q * CC + lane] = a1[q];
        if (two) zd[q * CC + 64 + lane] = a2[q];
    }
}

// ---------------------------------------------------------------- 7) fused: h_out = gelu(0.25*Z@Wtp + h@Wself + attr@Wattr)
// 625 blocks x 288 threads; 16 nodes/block staged in LDS; W streamed from L2.
__global__ __launch_bounds__(288) void k_agg2(const float* __restrict__ Z,
                                              const float* __restrict__ hin,
                                              const float* __restrict__ attr,
                                              const float* __restrict__ Wtp,
                                              const float* __restrict__ Wself,
                                              const float* __restrict__ Wattr,
                                              float* __restrict__ hout) {
    __shared__ float Ls[TROW][LW]; // 47360 B -> 3 blocks/CU
    int t = threadIdx.x;
    int n0 = blockIdx.x * TROW;

    // stage Z scaled by 0.25 (= 1/sqrt(NUM_NEIGHBORS)): 16 rows x 162 float4
    for (int idx = t; idx < TROW * 162; idx += 288) {
        int r = idx / 162, j = idx - r * 162;
        float4 v = *(const float4*)&Z[(size_t)(n0 + r) * KK + 4 * j];
        v.x *= 0.25f; v.y *= 0.25f; v.z *= 0.25f; v.w *= 0.25f;
        *(float4*)&Ls[r][4 * j] = v;
    }
    // stage h: 16 rows x 18 float4 = 288 -> one per thread
    {
        int r = t / 18, j = t - r * 18;
        *(float4*)&Ls[r][KK + 4 * j] = *(const float4*)&hin[(size_t)(n0 + r) * CC + 4 * j];
    }
    // stage attr: 16 rows x 4 float4
    if (t < 64) {
        int r = t >> 2, j = t & 3;
        *(float4*)&Ls[r][KK + CC + 4 * j] = *(const float4*)&attr[(size_t)(n0 + r) * AA + 4 * j];
    }
    __syncthreads();

    int cp = t % 72, y = t / 72; // y in 0..3, rows y+4*rr
    float acc[4] = {0.f, 0.f, 0.f, 0.f};

    for (int k = 0; k < KK; k += 4) {
        float w0 = Wtp[(k + 0) * CC + cp];
        float w1 = Wtp[(k + 1) * CC + cp];
        float w2 = Wtp[(k + 2) * CC + cp];
        float w3 = Wtp[(k + 3) * CC + cp];
#pragma unroll
        for (int rr = 0; rr < 4; ++rr) {
            float4 z = *(const float4*)&Ls[y + 4 * rr][k];
            acc[rr] += z.x * w0 + z.y * w1 + z.z * w2 + z.w * w3;
        }
    }
#pragma unroll
    for (int k = 0; k < CC; k += 4) {
        float w0 = Wself[(k + 0) * CC + cp];
        float w1 = Wself[(k + 1) * CC + cp];
        float w2 = Wself[(k + 2) * CC + cp];
        float w3 = Wself[(k + 3) * CC + cp];
#pragma unroll
        for (int rr = 0; rr < 4; ++rr) {
            float4 z = *(const float4*)&Ls[y + 4 * rr][KK + k];
            acc[rr] += z.x * w0 + z.y * w1 + z.z * w2 + z.w * w3;
        }
    }
#pragma unroll
    for (int k = 0; k < AA; k += 4) {
        float w0 = Wattr[(k + 0) * CC + cp];
        float w1 = Wattr[(k + 1) * CC + cp];
        float w2 = Wattr[(k + 2) * CC + cp];
        float w3 = Wattr[(k + 3) * CC + cp];
#pragma unroll
        for (int rr = 0; rr < 4; ++rr) {
            float4 z = *(const float4*)&Ls[y + 4 * rr][KK + CC + k];
            acc[rr] += z.x * w0 + z.y * w1 + z.z * w2 + z.w * w3;
        }
    }
#pragma unroll
    for (int rr = 0; rr < 4; ++rr) {
        int n = n0 + y + 4 * rr; // NN divisible by 16 -> always in range
        hout[(size_t)n * CC + cp] = gelu_tanh(acc[rr]);
    }
}

// ---------------------------------------------------------------- 8) out = segpool(h@W_out)/25
__global__ __launch_bounds__(256) void k_out(const float* __restrict__ h,
                                             const float* __restrict__ Wout,
                                             const int* __restrict__ batch,
                                             float* __restrict__ out) {
    __shared__ float sp[NBATCH * OO];
    int tid = threadIdx.x;
    for (int i = tid; i < NBATCH * OO; i += blockDim.x) sp[i] = 0.f;
    __syncthreads();
    int wave = tid >> 6, lane = tid & 63;
    const int WPB = 4;
    for (int n = blockIdx.x * WPB + wave; n < NN; n += gridDim.x * WPB) {
        const float* hr = &h[(size_t)n * CC];
        float acc = 0.f;
#pragma unroll 8
        for (int c = 0; c < CC; ++c) acc += hr[c] * Wout[c * OO + lane];
        atomicAdd(&sp[batch[n] * OO + lane], acc * (1.0f / 25.0f));
    }
    __syncthreads();
    for (int i = tid; i < NBATCH * OO; i += blockDim.x) {
        float v = sp[i];
        if (v != 0.f) atomicAdd(&out[i], v);
    }
}

// ---------------------------------------------------------------- launch
extern "C" void kernel_launch(void* const* d_in, const int* in_sizes, int n_in,
                              void* d_out, int out_size, void* d_ws, size_t ws_size,
                              hipStream_t stream) {
    const float* pos       = (const float*)d_in[0];
    const float* node_attr = (const float*)d_in[1];
    const int*   batch     = (const int*)d_in[2];
    const int*   esrc      = (const int*)d_in[3];
    const int*   edst      = (const int*)d_in[4];
    const float* W_in      = (const float*)d_in[5];
    const float* W_tp      = (const float*)d_in[6];
    const float* W_self    = (const float*)d_in[7];
    const float* W_attr    = (const float*)d_in[8];
    const float* fc1w      = (const float*)d_in[9];
    const float* fc1b      = (const float*)d_in[10];
    const float* fc2w      = (const float*)d_in[11];
    const float* W_out     = (const float*)d_in[12];
    float* out = (float*)d_out;

    char* p = (char*)d_ws;
    auto alloc = [&](size_t bytes) -> void* {
        void* r = (void*)p;
        p += (bytes + 255) & ~(size_t)255;
        return r;
    };
    int*   cnt   = (int*)alloc((size_t)NN * 4);
    int*   cur   = (int*)alloc((size_t)NN * 4);
    int*   off   = (int*)alloc((size_t)(NN + 1) * 4);
    int*   src_s = (int*)alloc((size_t)NE * 4);
    int*   dst_s = (int*)alloc((size_t)NE * 4);
    float* path  = (float*)alloc((size_t)LL * NE * PSTRIDE * 4);
    float* Z     = (float*)alloc((size_t)NN * KK * 4);
    float* h0    = (float*)alloc((size_t)NN * CC * 4);
    float* h1    = (float*)alloc((size_t)NN * CC * 4);

    hipMemsetAsync(cnt, 0, (size_t)NN * 4, stream);
    hipMemsetAsync(cur, 0, (size_t)NN * 4, stream);
    hipMemsetAsync(out, 0, (size_t)NBATCH * OO * 4, stream);

    k_hist<<<(NE + 255) / 256, 256, 0, stream>>>(pos, esrc, edst, cnt);
    k_scan<<<1, 256, 0, stream>>>(cnt, off);
    k_scatter2<<<(NE + 255) / 256, 256, 0, stream>>>(pos, esrc, edst, off, cur, src_s, dst_s);
    k_path<<<(NE + 255) / 256, 256, 0, stream>>>(pos, src_s, dst_s, fc1w, fc1b, fc2w, off, path);
    k_init<<<(NN * CC + 255) / 256, 256, 0, stream>>>(W_in, h0);

    const float* hin = h0;
    float* hout = h1;
    for (int l = 0; l < LL; ++l) {
        k_z2<<<(NN + 3) / 4, 256, 0, stream>>>(hin, path + (size_t)l * NE * PSTRIDE, src_s, off, Z);
        k_agg2<<<NN / TROW, 288, 0, stream>>>(
            Z, hin, node_attr,
            W_tp + (size_t)l * KK * CC,
            W_self + (size_t)l * CC * CC,
            W_attr + (size_t)l * AA * CC,
            hout);
        const float* tmp = hin; hin = hout; hout = (float*)tmp;
    }
    k_out<<<128, 256, 0, stream>>>(hin, W_out, batch, out);
}

// Round 4
// 448.530 us; speedup vs baseline: 3.8801x; 1.2551x over previous
//
#include <hip/hip_runtime.h>
#include <math.h>

#define NN 10000     // nodes
#define NE 160000    // edges
#define CC 72        // channels
#define AA 16        // node attr dim
#define LL 3         // layers
#define OO 64        // out dim
#define NBATCH 16
#define SH 9
#define FCN 100
#define KK (SH*CC)   // 648
#define KA 736       // concat K: 648 Z + 72 h + 16 attr = 23*32
#define PSTRIDE 12   // padded per-edge path stride (float4-aligned)
#define MT 16        // M tile (nodes per GEMM block)
#define KC 32        // K chunk
#define NCHK 23      // KA/KC

// ---------------------------------------------------------------- helpers
static __device__ __forceinline__ float gelu_tanh(float x) {
    float x3 = x * x * x;
    float inner = 0.7978845608028654f * (x + 0.044715f * x3);
    return 0.5f * x * (1.0f + tanhf(inner));
}

// ---------------------------------------------------------------- 1) histogram of kept edges per dst
__global__ void k_hist(const float* __restrict__ pos, const int* __restrict__ esrc,
                       const int* __restrict__ edst, int* __restrict__ cnt) {
    int e = blockIdx.x * blockDim.x + threadIdx.x;
    if (e >= NE) return;
    int s = esrc[e], d = edst[e];
    float dx = pos[3 * s] - pos[3 * d];
    float dy = pos[3 * s + 1] - pos[3 * d + 1];
    float dz = pos[3 * s + 2] - pos[3 * d + 2];
    float r = sqrtf(dx * dx + dy * dy + dz * dz);
    // t = r/2 >= 1 -> emb==0 -> silu(0)=0 (fc1_b==0) -> path==0: drop edge.
    if (r * 0.5f < 1.0f) atomicAdd(&cnt[d], 1);
}

// ---------------------------------------------------------------- 2) exclusive scan -> off[0..NN]
__global__ void k_scan(const int* __restrict__ cnt, int* __restrict__ off) {
    __shared__ int sa[256], sb[256];
    const int PER = 40;
    int t = threadIdx.x;
    int base = t * PER;
    int loc[PER];
    int run = 0;
#pragma unroll
    for (int i = 0; i < PER; ++i) {
        int idx = base + i;
        int v = (idx < NN) ? cnt[idx] : 0;
        loc[i] = run;
        run += v;
    }
    sa[t] = run;
    __syncthreads();
    int* in = sa; int* out = sb;
    for (int o = 1; o < 256; o <<= 1) {
        int v = in[t];
        if (t >= o) v += in[t - o];
        out[t] = v;
        __syncthreads();
        int* tmp = in; in = out; out = tmp;
    }
    int ebase = (t > 0) ? in[t - 1] : 0;
#pragma unroll
    for (int i = 0; i < PER; ++i) {
        int idx = base + i;
        if (idx <= NN) off[idx] = ebase + loc[i];
    }
}

// ---------------------------------------------------------------- 3) scatter kept edges dst-sorted
__global__ void k_scatter2(const float* __restrict__ pos, const int* __restrict__ esrc,
                           const int* __restrict__ edst, const int* __restrict__ off,
                           int* __restrict__ cur, int* __restrict__ src_s,
                           int* __restrict__ dst_s) {
    int e = blockIdx.x * blockDim.x + threadIdx.x;
    if (e >= NE) return;
    int s = esrc[e], d = edst[e];
    float dx = pos[3 * s] - pos[3 * d];
    float dy = pos[3 * s + 1] - pos[3 * d + 1];
    float dz = pos[3 * s + 2] - pos[3 * d + 2];
    float r = sqrtf(dx * dx + dy * dy + dz * dz);
    if (r * 0.5f < 1.0f) {
        int slot = off[d] + atomicAdd(&cur[d], 1);
        src_s[slot] = s;
        dst_s[slot] = d;
    }
}

// ---------------------------------------------------------------- 4) per-edge path[l][slot][12] (padded)
__global__ __launch_bounds__(256) void k_path(const float* __restrict__ pos,
                                              const int* __restrict__ src_s,
                                              const int* __restrict__ dst_s,
                                              const float* __restrict__ fc1w,
                                              const float* __restrict__ fc1b,
                                              const float* __restrict__ fc2w,
                                              const int* __restrict__ off,
                                              float* __restrict__ path) {
    __shared__ float w1[LL * FCN], b1[LL * FCN], w2[LL * FCN * SH];
    for (int i = threadIdx.x; i < LL * FCN; i += blockDim.x) { w1[i] = fc1w[i]; b1[i] = fc1b[i]; }
    for (int i = threadIdx.x; i < LL * FCN * SH; i += blockDim.x) w2[i] = fc2w[i];
    __syncthreads();
    int slot = blockIdx.x * blockDim.x + threadIdx.x;
    int total = off[NN];
    if (slot >= total) return;
    int s = src_s[slot], d = dst_s[slot];
    float dx = pos[3 * s] - pos[3 * d];
    float dy = pos[3 * s + 1] - pos[3 * d + 1];
    float dz = pos[3 * s + 2] - pos[3 * d + 2];
    float r = sqrtf(dx * dx + dy * dy + dz * dz);
    float inv = 1.0f / fmaxf(r, 1e-9f);
    float x = dx * inv, y = dy * inv, z = dz * inv;
    const float s3 = 1.7320508075688772f;
    const float s5 = 2.23606797749979f;
    const float s15 = 3.872983346207417f;
    float sh[SH];
    sh[0] = 1.0f;
    sh[1] = s3 * x;
    sh[2] = s3 * y;
    sh[3] = s3 * z;
    sh[4] = s15 * x * y;
    sh[5] = s15 * y * z;
    sh[6] = 0.5f * s5 * (3.0f * z * z - 1.0f);
    sh[7] = s15 * x * z;
    sh[8] = 0.5f * s15 * (x * x - y * y);
    float t = r * 0.5f;
    float emb = cosf(1.5707963267948966f * t);

    for (int l = 0; l < LL; ++l) {
        float u[SH];
#pragma unroll
        for (int q = 0; q < SH; ++q) u[q] = 0.f;
        const float* lw1 = &w1[l * FCN];
        const float* lb1 = &b1[l * FCN];
        const float* lw2 = &w2[l * FCN * SH];
        for (int f = 0; f < FCN; ++f) {
            float a = emb * lw1[f] + lb1[f];
            float si = a / (1.0f + expf(-a));
#pragma unroll
            for (int q = 0; q < SH; ++q) u[q] += si * lw2[f * SH + q];
        }
        float* pd = &path[((size_t)l * NE + slot) * PSTRIDE];
#pragma unroll
        for (int q = 0; q < SH; ++q) pd[q] = u[q] * sh[q];
        pd[9] = 0.f; pd[10] = 0.f; pd[11] = 0.f;
    }
}

// ---------------------------------------------------------------- 5) h init
__global__ void k_init(const float* __restrict__ W_in, float* __restrict__ h) {
    int i = blockIdx.x * blockDim.x + threadIdx.x;
    if (i < NN * CC) h[i] = W_in[i % CC];
}

// ---------------------------------------------------------------- 5b) Wcat[l] = [0.25*Wtp ; Wself ; Wattr]  (736 x 72)
__global__ void k_wcat(const float* __restrict__ Wtp, const float* __restrict__ Wself,
                       const float* __restrict__ Wattr, float* __restrict__ Wcat) {
    int i = blockIdx.x * blockDim.x + threadIdx.x;
    if (i >= LL * KA * CC) return;
    int l = i / (KA * CC);
    int rem = i - l * KA * CC;
    int k = rem / CC, c = rem - k * CC;
    float v;
    if (k < KK)            v = 0.25f * Wtp[(size_t)l * KK * CC + k * CC + c];
    else if (k < KK + CC)  v = Wself[(size_t)l * CC * CC + (k - KK) * CC + c];
    else                   v = Wattr[(size_t)l * AA * CC + (k - KK - CC) * CC + c];
    Wcat[i] = v;
}

// ---------------------------------------------------------------- 6) A[d] = [Z(d) | h(d) | attr(d)]  (wave per node)
__global__ __launch_bounds__(256) void k_z3(const float* __restrict__ h,
                                            const float* __restrict__ attr,
                                            const float* __restrict__ path_l,
                                            const int* __restrict__ src_s,
                                            const int* __restrict__ off,
                                            float* __restrict__ A) {
    int d = blockIdx.x * 4 + (threadIdx.x >> 6);
    int lane = threadIdx.x & 63;
    if (d >= NN) return;
    float a1[SH], a2[SH];
#pragma unroll
    for (int q = 0; q < SH; ++q) { a1[q] = 0.f; a2[q] = 0.f; }
    int b = off[d], e = off[d + 1];
    bool two = lane < (CC - 64); // 8 lanes handle a second channel
    for (int i = b; i < e; ++i) {
        int s = src_s[i];
        float hv1 = h[(size_t)s * CC + lane];
        float hv2 = two ? h[(size_t)s * CC + 64 + lane] : 0.f;
        const float* p = &path_l[(size_t)i * PSTRIDE];
        float4 p0 = *(const float4*)p;
        float4 p1 = *(const float4*)(p + 4);
        float p8 = p[8];
        a1[0] += p0.x * hv1; a2[0] += p0.x * hv2;
        a1[1] += p0.y * hv1; a2[1] += p0.y * hv2;
        a1[2] += p0.z * hv1; a2[2] += p0.z * hv2;
        a1[3] += p0.w * hv1; a2[3] += p0.w * hv2;
        a1[4] += p1.x * hv1; a2[4] += p1.x * hv2;
        a1[5] += p1.y * hv1; a2[5] += p1.y * hv2;
        a1[6] += p1.z * hv1; a2[6] += p1.z * hv2;
        a1[7] += p1.w * hv1; a2[7] += p1.w * hv2;
        a1[8] += p8 * hv1;   a2[8] += p8 * hv2;
    }
    float* ad = &A[(size_t)d * KA];
#pragma unroll
    for (int q = 0; q < SH; ++q) {
        ad[q * CC + lane] = a1[q];
        if (two) ad[q * CC + 64 + lane] = a2[q];
    }
    ad[KK + lane] = h[(size_t)d * CC + lane];
    if (two) ad[KK + 64 + lane] = h[(size_t)d * CC + 64 + lane];
    if (lane < AA) ad[KK + CC + lane] = attr[(size_t)d * AA + lane];
}

// ---------------------------------------------------------------- 7) hout = gelu(A @ Wcat)  -- LDS double-buffered GEMM
__global__ __launch_bounds__(288) void k_agg3(const float* __restrict__ A,
                                              const float* __restrict__ Wc,
                                              float* __restrict__ hout) {
    __shared__ float As[2][MT][KC + 4];
    __shared__ float Ws[2][KC][CC];
    int t = threadIdx.x;
    int n0 = blockIdx.x * MT;
    int cp = t % CC, y = t / CC; // y in 0..3

    // staging coordinates
    bool hasA = t < 128;
    int ar = t >> 3, aj = (t & 7) * 4;          // 16 rows x 8 float4
    int wr0 = t / 18, wc0 = (t % 18) * 4;       // 576 float4 over 2 rounds
    int wr1 = (t + 288) / 18, wc1 = ((t + 288) % 18) * 4;

    float4 va, vw0, vw1;
    // prologue: load + store chunk 0
    if (hasA) va = *(const float4*)&A[(size_t)(n0 + ar) * KA + aj];
    vw0 = *(const float4*)&Wc[(size_t)wr0 * CC + wc0];
    vw1 = *(const float4*)&Wc[(size_t)wr1 * CC + wc1];
    if (hasA) *(float4*)&As[0][ar][aj] = va;
    *(float4*)&Ws[0][wr0][wc0] = vw0;
    *(float4*)&Ws[0][wr1][wc1] = vw1;
    __syncthreads();

    float acc[4] = {0.f, 0.f, 0.f, 0.f};

    for (int ch = 0; ch < NCHK; ++ch) {
        int buf = ch & 1;
        // issue next chunk's global loads (latency hidden under compute)
        if (ch + 1 < NCHK) {
            int kb = (ch + 1) * KC;
            if (hasA) va = *(const float4*)&A[(size_t)(n0 + ar) * KA + kb + aj];
            vw0 = *(const float4*)&Wc[(size_t)(kb + wr0) * CC + wc0];
            vw1 = *(const float4*)&Wc[(size_t)(kb + wr1) * CC + wc1];
        }
#pragma unroll
        for (int kk = 0; kk < KC; kk += 4) {
            float w0 = Ws[buf][kk + 0][cp];
            float w1 = Ws[buf][kk + 1][cp];
            float w2 = Ws[buf][kk + 2][cp];
            float w3 = Ws[buf][kk + 3][cp];
#pragma unroll
            for (int rr = 0; rr < 4; ++rr) {
                float4 z = *(const float4*)&As[buf][y + 4 * rr][kk];
                acc[rr] += z.x * w0 + z.y * w1 + z.z * w2 + z.w * w3;
            }
        }
        if (ch + 1 < NCHK) {
            if (hasA) *(float4*)&As[buf ^ 1][ar][aj] = va;
            *(float4*)&Ws[buf ^ 1][wr0][wc0] = vw0;
            *(float4*)&Ws[buf ^ 1][wr1][wc1] = vw1;
        }
        __syncthreads();
    }

#pragma unroll
    for (int rr = 0; rr < 4; ++rr) {
        int n = n0 + y + 4 * rr; // NN % 16 == 0
        hout[(size_t)n * CC + cp] = gelu_tanh(acc[rr]);
    }
}

// ---------------------------------------------------------------- 8) out = segpool(h@W_out)/25
__global__ __launch_bounds__(256) void k_out(const float* __restrict__ h,
                                             const float* __restrict__ Wout,
                                             const int* __restrict__ batch,
                                             float* __restrict__ out) {
    __shared__ float sp[NBATCH * OO];
    int tid = threadIdx.x;
    for (int i = tid; i < NBATCH * OO; i += blockDim.x) sp[i] = 0.f;
    __syncthreads();
    int wave = tid >> 6, lane = tid & 63;
    const int WPB = 4;
    for (int n = blockIdx.x * WPB + wave; n < NN; n += gridDim.x * WPB) {
        const float* hr = &h[(size_t)n * CC];
        float acc = 0.f;
#pragma unroll 8
        for (int c = 0; c < CC; ++c) acc += hr[c] * Wout[c * OO + lane];
        atomicAdd(&sp[batch[n] * OO + lane], acc * (1.0f / 25.0f));
    }
    __syncthreads();
    for (int i = tid; i < NBATCH * OO; i += blockDim.x) {
        float v = sp[i];
        if (v != 0.f) atomicAdd(&out[i], v);
    }
}

// ---------------------------------------------------------------- launch
extern "C" void kernel_launch(void* const* d_in, const int* in_sizes, int n_in,
                              void* d_out, int out_size, void* d_ws, size_t ws_size,
                              hipStream_t stream) {
    const float* pos       = (const float*)d_in[0];
    const float* node_attr = (const float*)d_in[1];
    const int*   batch     = (const int*)d_in[2];
    const int*   esrc      = (const int*)d_in[3];
    const int*   edst      = (const int*)d_in[4];
    const float* W_in      = (const float*)d_in[5];
    const float* W_tp      = (const float*)d_in[6];
    const float* W_self    = (const float*)d_in[7];
    const float* W_attr    = (const float*)d_in[8];
    const float* fc1w      = (const float*)d_in[9];
    const float* fc1b      = (const float*)d_in[10];
    const float* fc2w      = (const float*)d_in[11];
    const float* W_out     = (const float*)d_in[12];
    float* out = (float*)d_out;

    char* p = (char*)d_ws;
    auto alloc = [&](size_t bytes) -> void* {
        void* r = (void*)p;
        p += (bytes + 255) & ~(size_t)255;
        return r;
    };
    int*   cnt   = (int*)alloc((size_t)NN * 4);
    int*   cur   = (int*)alloc((size_t)NN * 4);
    int*   off   = (int*)alloc((size_t)(NN + 1) * 4);
    int*   src_s = (int*)alloc((size_t)NE * 4);
    int*   dst_s = (int*)alloc((size_t)NE * 4);
    float* path  = (float*)alloc((size_t)LL * NE * PSTRIDE * 4);
    float* A     = (float*)alloc((size_t)NN * KA * 4);
    float* Wcat  = (float*)alloc((size_t)LL * KA * CC * 4);
    float* h0    = (float*)alloc((size_t)NN * CC * 4);
    float* h1    = (float*)alloc((size_t)NN * CC * 4);

    hipMemsetAsync(cnt, 0, (size_t)NN * 4, stream);
    hipMemsetAsync(cur, 0, (size_t)NN * 4, stream);
    hipMemsetAsync(out, 0, (size_t)NBATCH * OO * 4, stream);

    k_hist<<<(NE + 255) / 256, 256, 0, stream>>>(pos, esrc, edst, cnt);
    k_scan<<<1, 256, 0, stream>>>(cnt, off);
    k_scatter2<<<(NE + 255) / 256, 256, 0, stream>>>(pos, esrc, edst, off, cur, src_s, dst_s);
    k_path<<<(NE + 255) / 256, 256, 0, stream>>>(pos, src_s, dst_s, fc1w, fc1b, fc2w, off, path);
    k_init<<<(NN * CC + 255) / 256, 256, 0, stream>>>(W_in, h0);
    k_wcat<<<(LL * KA * CC + 255) / 256, 256, 0, stream>>>(W_tp, W_self, W_attr, Wcat);

    const float* hin = h0;
    float* hout = h1;
    for (int l = 0; l < LL; ++l) {
        k_z3<<<(NN + 3) / 4, 256, 0, stream>>>(hin, node_attr,
                                               path + (size_t)l * NE * PSTRIDE, src_s, off, A);
        k_agg3<<<NN / MT, 288, 0, stream>>>(A, Wcat + (size_t)l * KA * CC, hout);
        const float* tmp = hin; hin = hout; hout = (float*)tmp;
    }
    k_out<<<128, 256, 0, stream>>>(hin, W_out, batch, out);
}

// Round 5
// 335.034 us; speedup vs baseline: 5.1945x; 1.3388x over previous
//
#include <hip/hip_runtime.h>
#include <math.h>

#define NN 10000     // nodes
#define NE 160000    // edges
#define CC 72        // channels
#define AA 16        // node attr dim
#define LL 3         // layers
#define OO 64        // out dim
#define NBATCH 16
#define SH 9
#define FCN 100
#define KK (SH*CC)   // 648
#define KA 736       // concat K: 648 Z + 72 h + 16 attr = 23*32
#define NC8 80       // padded N for GEMM (72 -> 80)
#define PSTRIDE 12   // padded per-edge path stride (float4-aligned)
#define KC 32        // K chunk
#define NCHK 23      // KA/KC
#define MT 32        // GEMM M tile

// ---------------------------------------------------------------- helpers
static __device__ __forceinline__ float gelu_tanh(float x) {
    float x3 = x * x * x;
    float inner = 0.7978845608028654f * (x + 0.044715f * x3);
    return 0.5f * x * (1.0f + tanhf(inner));
}

// ---------------------------------------------------------------- 1) histogram of kept edges per dst
__global__ void k_hist(const float* __restrict__ pos, const int* __restrict__ esrc,
                       const int* __restrict__ edst, int* __restrict__ cnt) {
    int e = blockIdx.x * blockDim.x + threadIdx.x;
    if (e >= NE) return;
    int s = esrc[e], d = edst[e];
    float dx = pos[3 * s] - pos[3 * d];
    float dy = pos[3 * s + 1] - pos[3 * d + 1];
    float dz = pos[3 * s + 2] - pos[3 * d + 2];
    float r = sqrtf(dx * dx + dy * dy + dz * dz);
    // t = r/2 >= 1 -> emb==0 -> silu(0)=0 (fc1_b==0) -> path==0: drop edge.
    if (r * 0.5f < 1.0f) atomicAdd(&cnt[d], 1);
}

// ---------------------------------------------------------------- 2) exclusive scan -> off[0..NN]
__global__ void k_scan(const int* __restrict__ cnt, int* __restrict__ off) {
    __shared__ int sa[256], sb[256];
    const int PER = 40;
    int t = threadIdx.x;
    int base = t * PER;
    int loc[PER];
    int run = 0;
#pragma unroll
    for (int i = 0; i < PER; ++i) {
        int idx = base + i;
        int v = (idx < NN) ? cnt[idx] : 0;
        loc[i] = run;
        run += v;
    }
    sa[t] = run;
    __syncthreads();
    int* in = sa; int* out = sb;
    for (int o = 1; o < 256; o <<= 1) {
        int v = in[t];
        if (t >= o) v += in[t - o];
        out[t] = v;
        __syncthreads();
        int* tmp = in; in = out; out = tmp;
    }
    int ebase = (t > 0) ? in[t - 1] : 0;
#pragma unroll
    for (int i = 0; i < PER; ++i) {
        int idx = base + i;
        if (idx <= NN) off[idx] = ebase + loc[i];
    }
}

// ---------------------------------------------------------------- 3) scatter kept edges dst-sorted
__global__ void k_scatter2(const float* __restrict__ pos, const int* __restrict__ esrc,
                           const int* __restrict__ edst, const int* __restrict__ off,
                           int* __restrict__ cur, int* __restrict__ src_s,
                           int* __restrict__ dst_s) {
    int e = blockIdx.x * blockDim.x + threadIdx.x;
    if (e >= NE) return;
    int s = esrc[e], d = edst[e];
    float dx = pos[3 * s] - pos[3 * d];
    float dy = pos[3 * s + 1] - pos[3 * d + 1];
    float dz = pos[3 * s + 2] - pos[3 * d + 2];
    float r = sqrtf(dx * dx + dy * dy + dz * dz);
    if (r * 0.5f < 1.0f) {
        int slot = off[d] + atomicAdd(&cur[d], 1);
        src_s[slot] = s;
        dst_s[slot] = d;
    }
}

// ---------------------------------------------------------------- 4) per-edge path[l][slot][12] (padded)
__global__ __launch_bounds__(256) void k_path(const float* __restrict__ pos,
                                              const int* __restrict__ src_s,
                                              const int* __restrict__ dst_s,
                                              const float* __restrict__ fc1w,
                                              const float* __restrict__ fc1b,
                                              const float* __restrict__ fc2w,
                                              const int* __restrict__ off,
                                              float* __restrict__ path) {
    __shared__ float w1[LL * FCN], b1[LL * FCN], w2[LL * FCN * SH];
    for (int i = threadIdx.x; i < LL * FCN; i += blockDim.x) { w1[i] = fc1w[i]; b1[i] = fc1b[i]; }
    for (int i = threadIdx.x; i < LL * FCN * SH; i += blockDim.x) w2[i] = fc2w[i];
    __syncthreads();
    int slot = blockIdx.x * blockDim.x + threadIdx.x;
    int total = off[NN];
    if (slot >= total) return;
    int s = src_s[slot], d = dst_s[slot];
    float dx = pos[3 * s] - pos[3 * d];
    float dy = pos[3 * s + 1] - pos[3 * d + 1];
    float dz = pos[3 * s + 2] - pos[3 * d + 2];
    float r = sqrtf(dx * dx + dy * dy + dz * dz);
    float inv = 1.0f / fmaxf(r, 1e-9f);
    float x = dx * inv, y = dy * inv, z = dz * inv;
    const float s3 = 1.7320508075688772f;
    const float s5 = 2.23606797749979f;
    const float s15 = 3.872983346207417f;
    float sh[SH];
    sh[0] = 1.0f;
    sh[1] = s3 * x;
    sh[2] = s3 * y;
    sh[3] = s3 * z;
    sh[4] = s15 * x * y;
    sh[5] = s15 * y * z;
    sh[6] = 0.5f * s5 * (3.0f * z * z - 1.0f);
    sh[7] = s15 * x * z;
    sh[8] = 0.5f * s15 * (x * x - y * y);
    float t = r * 0.5f;
    float emb = cosf(1.5707963267948966f * t);

    for (int l = 0; l < LL; ++l) {
        float u[SH];
#pragma unroll
        for (int q = 0; q < SH; ++q) u[q] = 0.f;
        const float* lw1 = &w1[l * FCN];
        const float* lb1 = &b1[l * FCN];
        const float* lw2 = &w2[l * FCN * SH];
        for (int f = 0; f < FCN; ++f) {
            float a = emb * lw1[f] + lb1[f];
            float si = a / (1.0f + expf(-a));
#pragma unroll
            for (int q = 0; q < SH; ++q) u[q] += si * lw2[f * SH + q];
        }
        float* pd = &path[((size_t)l * NE + slot) * PSTRIDE];
#pragma unroll
        for (int q = 0; q < SH; ++q) pd[q] = u[q] * sh[q];
        pd[9] = 0.f; pd[10] = 0.f; pd[11] = 0.f;
    }
}

// ---------------------------------------------------------------- 5) h init
__global__ void k_init(const float* __restrict__ W_in, float* __restrict__ h) {
    int i = blockIdx.x * blockDim.x + threadIdx.x;
    if (i < NN * CC) h[i] = W_in[i % CC];
}

// ---------------------------------------------------------------- 5b) Wcat80[l][k][c80] = [0.25*Wtp ; Wself ; Wattr], cols padded to 80
__global__ void k_wcat(const float* __restrict__ Wtp, const float* __restrict__ Wself,
                       const float* __restrict__ Wattr, float* __restrict__ Wcat) {
    int i = blockIdx.x * blockDim.x + threadIdx.x;
    if (i >= LL * KA * NC8) return;
    int l = i / (KA * NC8);
    int rem = i - l * (KA * NC8);
    int k = rem / NC8, c = rem - k * NC8;
    float v = 0.f;
    if (c < CC) {
        if (k < KK)            v = 0.25f * Wtp[(size_t)l * KK * CC + k * CC + c];
        else if (k < KK + CC)  v = Wself[(size_t)l * CC * CC + (k - KK) * CC + c];
        else                   v = Wattr[(size_t)l * AA * CC + (k - KK - CC) * CC + c];
    }
    Wcat[i] = v;
}

// ---------------------------------------------------------------- 6) A[d] = [Z(d) | h(d) | attr(d)]  (wave per node)
__global__ __launch_bounds__(256) void k_z3(const float* __restrict__ h,
                                            const float* __restrict__ attr,
                                            const float* __restrict__ path_l,
                                            const int* __restrict__ src_s,
                                            const int* __restrict__ off,
                                            float* __restrict__ A) {
    int d = blockIdx.x * 4 + (threadIdx.x >> 6);
    int lane = threadIdx.x & 63;
    if (d >= NN) return;
    float a1[SH], a2[SH];
#pragma unroll
    for (int q = 0; q < SH; ++q) { a1[q] = 0.f; a2[q] = 0.f; }
    int b = off[d], e = off[d + 1];
    bool two = lane < (CC - 64);
    for (int i = b; i < e; ++i) {
        int s = src_s[i];
        float hv1 = h[(size_t)s * CC + lane];
        float hv2 = two ? h[(size_t)s * CC + 64 + lane] : 0.f;
        const float* p = &path_l[(size_t)i * PSTRIDE];
        float4 p0 = *(const float4*)p;
        float4 p1 = *(const float4*)(p + 4);
        float p8 = p[8];
        a1[0] += p0.x * hv1; a2[0] += p0.x * hv2;
        a1[1] += p0.y * hv1; a2[1] += p0.y * hv2;
        a1[2] += p0.z * hv1; a2[2] += p0.z * hv2;
        a1[3] += p0.w * hv1; a2[3] += p0.w * hv2;
        a1[4] += p1.x * hv1; a2[4] += p1.x * hv2;
        a1[5] += p1.y * hv1; a2[5] += p1.y * hv2;
        a1[6] += p1.z * hv1; a2[6] += p1.z * hv2;
        a1[7] += p1.w * hv1; a2[7] += p1.w * hv2;
        a1[8] += p8 * hv1;   a2[8] += p8 * hv2;
    }
    float* ad = &A[(size_t)d * KA];
#pragma unroll
    for (int q = 0; q < SH; ++q) {
        ad[q * CC + lane] = a1[q];
        if (two) ad[q * CC + 64 + lane] = a2[q];
    }
    ad[KK + lane] = h[(size_t)d * CC + lane];
    if (two) ad[KK + 64 + lane] = h[(size_t)d * CC + 64 + lane];
    if (lane < AA) ad[KK + CC + lane] = attr[(size_t)d * AA + lane];
}

// ---------------------------------------------------------------- 7) split-K outer-product GEMM: P[g] = A[:, Kg] @ Wc[Kg, :]
// 320 threads = 5 waves; thread = (cg 0..19, ry 0..15): 2 rows x 4 cols.
__global__ __launch_bounds__(320) void k_agg4(const float* __restrict__ A,
                                              const float* __restrict__ Wc,
                                              float* __restrict__ P) {
    __shared__ float As[2][KC][36];   // [k][m], padded 36: conflict-free
    __shared__ float Ws[2][KC][84];   // [k][c80], padded 84
    int t = threadIdx.x;
    int n0 = blockIdx.x * MT;
    int g = blockIdx.y;
    int cg = t / 16, ry = t % 16;

    int c0 = g * 12;
    int nch = g ? 11 : 12;

    // staging coords
    int ar = t & 31, akq = t >> 5;            // t<256: A row ar, k-quad akq
    int wkr0 = t / 20,        wcj0 = t % 20;  // W: 32 rows x 20 float4, 2 rounds
    int wkr1 = (t + 320) / 20, wcj1 = (t + 320) % 20;
    int anc = min(n0 + ar, NN - 1);

    float4 va, vw0, vw1;
    // prologue: chunk 0
    {
        int kb = c0 * KC;
        if (t < 256) va = *(const float4*)&A[(size_t)anc * KA + kb + 4 * akq];
        vw0 = *(const float4*)&Wc[(size_t)(kb + wkr0) * NC8 + 4 * wcj0];
        vw1 = *(const float4*)&Wc[(size_t)(kb + wkr1) * NC8 + 4 * wcj1];
        if (t < 256) {
            As[0][4 * akq + 0][ar] = va.x;
            As[0][4 * akq + 1][ar] = va.y;
            As[0][4 * akq + 2][ar] = va.z;
            As[0][4 * akq + 3][ar] = va.w;
        }
        *(float4*)&Ws[0][wkr0][4 * wcj0] = vw0;
        *(float4*)&Ws[0][wkr1][4 * wcj1] = vw1;
    }
    __syncthreads();

    float acc[2][4];
#pragma unroll
    for (int j = 0; j < 2; ++j)
#pragma unroll
        for (int c = 0; c < 4; ++c) acc[j][c] = 0.f;

    for (int ch = 0; ch < nch; ++ch) {
        int buf = ch & 1;
        if (ch + 1 < nch) {
            int kb = (c0 + ch + 1) * KC;
            if (t < 256) va = *(const float4*)&A[(size_t)anc * KA + kb + 4 * akq];
            vw0 = *(const float4*)&Wc[(size_t)(kb + wkr0) * NC8 + 4 * wcj0];
            vw1 = *(const float4*)&Wc[(size_t)(kb + wkr1) * NC8 + 4 * wcj1];
        }
#pragma unroll
        for (int kk = 0; kk < KC; ++kk) {
            float4 w = *(const float4*)&Ws[buf][kk][4 * cg];
            float2 a = *(const float2*)&As[buf][kk][2 * ry];
            acc[0][0] += a.x * w.x; acc[0][1] += a.x * w.y;
            acc[0][2] += a.x * w.z; acc[0][3] += a.x * w.w;
            acc[1][0] += a.y * w.x; acc[1][1] += a.y * w.y;
            acc[1][2] += a.y * w.z; acc[1][3] += a.y * w.w;
        }
        if (ch + 1 < nch) {
            int nb = buf ^ 1;
            if (t < 256) {
                As[nb][4 * akq + 0][ar] = va.x;
                As[nb][4 * akq + 1][ar] = va.y;
                As[nb][4 * akq + 2][ar] = va.z;
                As[nb][4 * akq + 3][ar] = va.w;
            }
            *(float4*)&Ws[nb][wkr0][4 * wcj0] = vw0;
            *(float4*)&Ws[nb][wkr1][4 * wcj1] = vw1;
        }
        __syncthreads();
    }

    if (cg < 18) { // cols 4cg..4cg+3 < 72
        int r0 = n0 + 2 * ry;
        float* pb = &P[(size_t)g * NN * CC];
        if (r0 < NN)
            *(float4*)&pb[(size_t)r0 * CC + 4 * cg] =
                make_float4(acc[0][0], acc[0][1], acc[0][2], acc[0][3]);
        if (r0 + 1 < NN)
            *(float4*)&pb[(size_t)(r0 + 1) * CC + 4 * cg] =
                make_float4(acc[1][0], acc[1][1], acc[1][2], acc[1][3]);
    }
}

// ---------------------------------------------------------------- 7b) hout = gelu(P0 + P1)
__global__ void k_gelu(const float* __restrict__ P, float* __restrict__ hout) {
    int i = blockIdx.x * blockDim.x + threadIdx.x;
    if (i < NN * CC) hout[i] = gelu_tanh(P[i] + P[NN * CC + i]);
}

// ---------------------------------------------------------------- 8) out = segpool(h@W_out)/25
__global__ __launch_bounds__(256) void k_out(const float* __restrict__ h,
                                             const float* __restrict__ Wout,
                                             const int* __restrict__ batch,
                                             float* __restrict__ out) {
    __shared__ float sp[NBATCH * OO];
    int tid = threadIdx.x;
    for (int i = tid; i < NBATCH * OO; i += blockDim.x) sp[i] = 0.f;
    __syncthreads();
    int wave = tid >> 6, lane = tid & 63;
    const int WPB = 4;
    for (int n = blockIdx.x * WPB + wave; n < NN; n += gridDim.x * WPB) {
        const float* hr = &h[(size_t)n * CC];
        float acc = 0.f;
#pragma unroll 8
        for (int c = 0; c < CC; ++c) acc += hr[c] * Wout[c * OO + lane];
        atomicAdd(&sp[batch[n] * OO + lane], acc * (1.0f / 25.0f));
    }
    __syncthreads();
    for (int i = tid; i < NBATCH * OO; i += blockDim.x) {
        float v = sp[i];
        if (v != 0.f) atomicAdd(&out[i], v);
    }
}

// ---------------------------------------------------------------- launch
extern "C" void kernel_launch(void* const* d_in, const int* in_sizes, int n_in,
                              void* d_out, int out_size, void* d_ws, size_t ws_size,
                              hipStream_t stream) {
    const float* pos       = (const float*)d_in[0];
    const float* node_attr = (const float*)d_in[1];
    const int*   batch     = (const int*)d_in[2];
    const int*   esrc      = (const int*)d_in[3];
    const int*   edst      = (const int*)d_in[4];
    const float* W_in      = (const float*)d_in[5];
    const float* W_tp      = (const float*)d_in[6];
    const float* W_self    = (const float*)d_in[7];
    const float* W_attr    = (const float*)d_in[8];
    const float* fc1w      = (const float*)d_in[9];
    const float* fc1b      = (const float*)d_in[10];
    const float* fc2w      = (const float*)d_in[11];
    const float* W_out     = (const float*)d_in[12];
    float* out = (float*)d_out;

    char* p = (char*)d_ws;
    auto alloc = [&](size_t bytes) -> void* {
        void* r = (void*)p;
        p += (bytes + 255) & ~(size_t)255;
        return r;
    };
    int*   cnt   = (int*)alloc((size_t)NN * 4);
    int*   cur   = (int*)alloc((size_t)NN * 4);
    int*   off   = (int*)alloc((size_t)(NN + 1) * 4);
    int*   src_s = (int*)alloc((size_t)NE * 4);
    int*   dst_s = (int*)alloc((size_t)NE * 4);
    float* path  = (float*)alloc((size_t)LL * NE * PSTRIDE * 4);
    float* A     = (float*)alloc((size_t)NN * KA * 4);
    float* Wcat  = (float*)alloc((size_t)LL * KA * NC8 * 4);
    float* P     = (float*)alloc((size_t)2 * NN * CC * 4);
    float* h0    = (float*)alloc((size_t)NN * CC * 4);
    float* h1    = (float*)alloc((size_t)NN * CC * 4);

    hipMemsetAsync(cnt, 0, (size_t)NN * 4, stream);
    hipMemsetAsync(cur, 0, (size_t)NN * 4, stream);
    hipMemsetAsync(out, 0, (size_t)NBATCH * OO * 4, stream);

    k_hist<<<(NE + 255) / 256, 256, 0, stream>>>(pos, esrc, edst, cnt);
    k_scan<<<1, 256, 0, stream>>>(cnt, off);
    k_scatter2<<<(NE + 255) / 256, 256, 0, stream>>>(pos, esrc, edst, off, cur, src_s, dst_s);
    k_path<<<(NE + 255) / 256, 256, 0, stream>>>(pos, src_s, dst_s, fc1w, fc1b, fc2w, off, path);
    k_init<<<(NN * CC + 255) / 256, 256, 0, stream>>>(W_in, h0);
    k_wcat<<<(LL * KA * NC8 + 255) / 256, 256, 0, stream>>>(W_tp, W_self, W_attr, Wcat);

    const float* hin = h0;
    float* hout = h1;
    for (int l = 0; l < LL; ++l) {
        k_z3<<<(NN + 3) / 4, 256, 0, stream>>>(hin, node_attr,
                                               path + (size_t)l * NE * PSTRIDE, src_s, off, A);
        k_agg4<<<dim3((NN + MT - 1) / MT, 2), 320, 0, stream>>>(
            A, Wcat + (size_t)l * KA * NC8, P);
        k_gelu<<<(NN * CC + 255) / 256, 256, 0, stream>>>(P, hout);
        const float* tmp = hin; hin = hout; hout = (float*)tmp;
    }
    k_out<<<128, 256, 0, stream>>>(hin, W_out, batch, out);
}

// Round 6
// 317.813 us; speedup vs baseline: 5.4760x; 1.0542x over previous
//
#include <hip/hip_runtime.h>
#include <math.h>

#define NN 10000     // nodes
#define NE 160000    // edges
#define CC 72        // channels
#define AA 16        // node attr dim
#define LL 3         // layers
#define OO 64        // out dim
#define NBATCH 16
#define SH 9
#define FCN 100
#define KK (SH*CC)   // 648
#define KA 736       // concat K: 648 Z + 72 h + 16 attr = 23*32
#define NC8 80       // padded N for GEMM (72 -> 80)
#define PSTRIDE 12   // padded per-edge path stride (float4-aligned)
#define KC 32        // K chunk
#define NCHK 23      // KA/KC
#define MT 32        // GEMM M tile
#define NB 1024      // u-table bins over t = r/MAX_RADIUS

// ---------------------------------------------------------------- helpers
static __device__ __forceinline__ float gelu_tanh(float x) {
    float x3 = x * x * x;
    float inner = 0.7978845608028654f * (x + 0.044715f * x3);
    return 0.5f * x * (1.0f + tanhf(inner));
}

// ---------------------------------------------------------------- 1) histogram of kept edges per dst
__global__ void k_hist(const float* __restrict__ pos, const int* __restrict__ esrc,
                       const int* __restrict__ edst, int* __restrict__ cnt) {
    int e = blockIdx.x * blockDim.x + threadIdx.x;
    if (e >= NE) return;
    int s = esrc[e], d = edst[e];
    float dx = pos[3 * s] - pos[3 * d];
    float dy = pos[3 * s + 1] - pos[3 * d + 1];
    float dz = pos[3 * s + 2] - pos[3 * d + 2];
    float r = sqrtf(dx * dx + dy * dy + dz * dz);
    // t = r/2 >= 1 -> emb==0 -> silu(0)=0 (fc1_b==0) -> path==0: drop edge.
    if (r * 0.5f < 1.0f) atomicAdd(&cnt[d], 1);
}

// ---------------------------------------------------------------- 2) exclusive scan -> off[0..NN]
__global__ void k_scan(const int* __restrict__ cnt, int* __restrict__ off) {
    __shared__ int sa[256], sb[256];
    const int PER = 40;
    int t = threadIdx.x;
    int base = t * PER;
    int loc[PER];
    int run = 0;
#pragma unroll
    for (int i = 0; i < PER; ++i) {
        int idx = base + i;
        int v = (idx < NN) ? cnt[idx] : 0;
        loc[i] = run;
        run += v;
    }
    sa[t] = run;
    __syncthreads();
    int* in = sa; int* out = sb;
    for (int o = 1; o < 256; o <<= 1) {
        int v = in[t];
        if (t >= o) v += in[t - o];
        out[t] = v;
        __syncthreads();
        int* tmp = in; in = out; out = tmp;
    }
    int ebase = (t > 0) ? in[t - 1] : 0;
#pragma unroll
    for (int i = 0; i < PER; ++i) {
        int idx = base + i;
        if (idx <= NN) off[idx] = ebase + loc[i];
    }
}

// ---------------------------------------------------------------- 3) scatter kept edges dst-sorted
__global__ void k_scatter2(const float* __restrict__ pos, const int* __restrict__ esrc,
                           const int* __restrict__ edst, const int* __restrict__ off,
                           int* __restrict__ cur, int* __restrict__ src_s,
                           int* __restrict__ dst_s) {
    int e = blockIdx.x * blockDim.x + threadIdx.x;
    if (e >= NE) return;
    int s = esrc[e], d = edst[e];
    float dx = pos[3 * s] - pos[3 * d];
    float dy = pos[3 * s + 1] - pos[3 * d + 1];
    float dz = pos[3 * s + 2] - pos[3 * d + 2];
    float r = sqrtf(dx * dx + dy * dy + dz * dz);
    if (r * 0.5f < 1.0f) {
        int slot = off[d] + atomicAdd(&cur[d], 1);
        src_s[slot] = s;
        dst_s[slot] = d;
    }
}

// ---------------------------------------------------------------- 4a) u-table: U[l][b][12], b over t in [0,1]
__global__ void k_utab(const float* __restrict__ fc1w, const float* __restrict__ fc1b,
                       const float* __restrict__ fc2w, float* __restrict__ U) {
    int i = blockIdx.x * blockDim.x + threadIdx.x;
    if (i >= LL * (NB + 1)) return;
    int l = i / (NB + 1), b = i - l * (NB + 1);
    float emb = cosf(1.5707963267948966f * ((float)b / (float)NB));
    float u[SH];
#pragma unroll
    for (int q = 0; q < SH; ++q) u[q] = 0.f;
    const float* w1 = &fc1w[l * FCN];
    const float* b1 = &fc1b[l * FCN];
    const float* w2 = &fc2w[l * FCN * SH];
    for (int f = 0; f < FCN; ++f) {
        float a = emb * w1[f] + b1[f];
        float si = a / (1.0f + expf(-a));
#pragma unroll
        for (int q = 0; q < SH; ++q) u[q] += si * w2[f * SH + q];
    }
    float* ud = &U[(size_t)i * 12];
#pragma unroll
    for (int q = 0; q < SH; ++q) ud[q] = u[q];
    ud[9] = 0.f; ud[10] = 0.f; ud[11] = 0.f;
}

// ---------------------------------------------------------------- 4b) per-edge path via table lerp
__global__ __launch_bounds__(256) void k_path2(const float* __restrict__ pos,
                                               const int* __restrict__ src_s,
                                               const int* __restrict__ dst_s,
                                               const float* __restrict__ U,
                                               const int* __restrict__ off,
                                               float* __restrict__ path) {
    int slot = blockIdx.x * blockDim.x + threadIdx.x;
    if (slot >= off[NN]) return;
    int s = src_s[slot], d = dst_s[slot];
    float dx = pos[3 * s] - pos[3 * d];
    float dy = pos[3 * s + 1] - pos[3 * d + 1];
    float dz = pos[3 * s + 2] - pos[3 * d + 2];
    float r = sqrtf(dx * dx + dy * dy + dz * dz);
    float inv = 1.0f / fmaxf(r, 1e-9f);
    float x = dx * inv, y = dy * inv, z = dz * inv;
    const float s3 = 1.7320508075688772f;
    const float s5 = 2.23606797749979f;
    const float s15 = 3.872983346207417f;
    float sh[SH];
    sh[0] = 1.0f;
    sh[1] = s3 * x;
    sh[2] = s3 * y;
    sh[3] = s3 * z;
    sh[4] = s15 * x * y;
    sh[5] = s15 * y * z;
    sh[6] = 0.5f * s5 * (3.0f * z * z - 1.0f);
    sh[7] = s15 * x * z;
    sh[8] = 0.5f * s15 * (x * x - y * y);

    float fb = r * 0.5f * (float)NB;  // < NB for kept edges (same arithmetic as filter)
    int b0 = (int)fb;
    float fr = fb - (float)b0;

#pragma unroll
    for (int l = 0; l < LL; ++l) {
        const float* t0 = &U[((size_t)l * (NB + 1) + b0) * 12];
        float4 a0 = *(const float4*)(t0 + 0);
        float4 a1 = *(const float4*)(t0 + 4);
        float  a2 = t0[8];
        float4 c0 = *(const float4*)(t0 + 12);
        float4 c1 = *(const float4*)(t0 + 16);
        float  c2 = t0[20];
        float u0 = a0.x + fr * (c0.x - a0.x);
        float u1 = a0.y + fr * (c0.y - a0.y);
        float u2 = a0.z + fr * (c0.z - a0.z);
        float u3 = a0.w + fr * (c0.w - a0.w);
        float u4 = a1.x + fr * (c1.x - a1.x);
        float u5 = a1.y + fr * (c1.y - a1.y);
        float u6 = a1.z + fr * (c1.z - a1.z);
        float u7 = a1.w + fr * (c1.w - a1.w);
        float u8 = a2   + fr * (c2   - a2);
        float* pd = &path[((size_t)l * NE + slot) * PSTRIDE];
        *(float4*)(pd + 0) = make_float4(u0 * sh[0], u1 * sh[1], u2 * sh[2], u3 * sh[3]);
        *(float4*)(pd + 4) = make_float4(u4 * sh[4], u5 * sh[5], u6 * sh[6], u7 * sh[7]);
        *(float4*)(pd + 8) = make_float4(u8 * sh[8], 0.f, 0.f, 0.f);
    }
}

// ---------------------------------------------------------------- 5) h init
__global__ void k_init(const float* __restrict__ W_in, float* __restrict__ h) {
    int i = blockIdx.x * blockDim.x + threadIdx.x;
    if (i < NN * CC) h[i] = W_in[i % CC];
}

// ---------------------------------------------------------------- 5b) Wcat80[l][k][c80] = [0.25*Wtp ; Wself ; Wattr], cols padded to 80
__global__ void k_wcat(const float* __restrict__ Wtp, const float* __restrict__ Wself,
                       const float* __restrict__ Wattr, float* __restrict__ Wcat) {
    int i = blockIdx.x * blockDim.x + threadIdx.x;
    if (i >= LL * KA * NC8) return;
    int l = i / (KA * NC8);
    int rem = i - l * (KA * NC8);
    int k = rem / NC8, c = rem - k * NC8;
    float v = 0.f;
    if (c < CC) {
        if (k < KK)            v = 0.25f * Wtp[(size_t)l * KK * CC + k * CC + c];
        else if (k < KK + CC)  v = Wself[(size_t)l * CC * CC + (k - KK) * CC + c];
        else                   v = Wattr[(size_t)l * AA * CC + (k - KK - CC) * CC + c];
    }
    Wcat[i] = v;
}

// ---------------------------------------------------------------- 6) A[d] = [Z(d) | h(d) | attr(d)]  (wave per node)
__global__ __launch_bounds__(256) void k_z3(const float* __restrict__ h,
                                            const float* __restrict__ attr,
                                            const float* __restrict__ path_l,
                                            const int* __restrict__ src_s,
                                            const int* __restrict__ off,
                                            float* __restrict__ A) {
    int d = blockIdx.x * 4 + (threadIdx.x >> 6);
    int lane = threadIdx.x & 63;
    if (d >= NN) return;
    float a1[SH], a2[SH];
#pragma unroll
    for (int q = 0; q < SH; ++q) { a1[q] = 0.f; a2[q] = 0.f; }
    int b = off[d], e = off[d + 1];
    bool two = lane < (CC - 64);
    for (int i = b; i < e; ++i) {
        int s = src_s[i];
        float hv1 = h[(size_t)s * CC + lane];
        float hv2 = two ? h[(size_t)s * CC + 64 + lane] : 0.f;
        const float* p = &path_l[(size_t)i * PSTRIDE];
        float4 p0 = *(const float4*)p;
        float4 p1 = *(const float4*)(p + 4);
        float p8 = p[8];
        a1[0] += p0.x * hv1; a2[0] += p0.x * hv2;
        a1[1] += p0.y * hv1; a2[1] += p0.y * hv2;
        a1[2] += p0.z * hv1; a2[2] += p0.z * hv2;
        a1[3] += p0.w * hv1; a2[3] += p0.w * hv2;
        a1[4] += p1.x * hv1; a2[4] += p1.x * hv2;
        a1[5] += p1.y * hv1; a2[5] += p1.y * hv2;
        a1[6] += p1.z * hv1; a2[6] += p1.z * hv2;
        a1[7] += p1.w * hv1; a2[7] += p1.w * hv2;
        a1[8] += p8 * hv1;   a2[8] += p8 * hv2;
    }
    float* ad = &A[(size_t)d * KA];
#pragma unroll
    for (int q = 0; q < SH; ++q) {
        ad[q * CC + lane] = a1[q];
        if (two) ad[q * CC + 64 + lane] = a2[q];
    }
    ad[KK + lane] = h[(size_t)d * CC + lane];
    if (two) ad[KK + 64 + lane] = h[(size_t)d * CC + 64 + lane];
    if (lane < AA) ad[KK + CC + lane] = attr[(size_t)d * AA + lane];
}

// ---------------------------------------------------------------- 7) split-K outer-product GEMM: P[g] = A[:, Kg] @ Wc[Kg, :]
// 320 threads = 5 waves; thread = (cg 0..19, ry 0..15): 2 rows x 4 cols.
__global__ __launch_bounds__(320) void k_agg4(const float* __restrict__ A,
                                              const float* __restrict__ Wc,
                                              float* __restrict__ P) {
    __shared__ float As[2][KC][36];   // [k][m], padded 36: conflict-free
    __shared__ float Ws[2][KC][84];   // [k][c80], padded 84
    int t = threadIdx.x;
    int n0 = blockIdx.x * MT;
    int g = blockIdx.y;
    int cg = t / 16, ry = t % 16;

    int c0 = g * 12;
    int nch = g ? 11 : 12;

    // staging coords
    int ar = t & 31, akq = t >> 5;            // t<256: A row ar, k-quad akq
    int wkr0 = t / 20,        wcj0 = t % 20;  // W: 32 rows x 20 float4, 2 rounds
    int wkr1 = (t + 320) / 20, wcj1 = (t + 320) % 20;
    int anc = min(n0 + ar, NN - 1);

    float4 va, vw0, vw1;
    // prologue: chunk 0
    {
        int kb = c0 * KC;
        if (t < 256) va = *(const float4*)&A[(size_t)anc * KA + kb + 4 * akq];
        vw0 = *(const float4*)&Wc[(size_t)(kb + wkr0) * NC8 + 4 * wcj0];
        vw1 = *(const float4*)&Wc[(size_t)(kb + wkr1) * NC8 + 4 * wcj1];
        if (t < 256) {
            As[0][4 * akq + 0][ar] = va.x;
            As[0][4 * akq + 1][ar] = va.y;
            As[0][4 * akq + 2][ar] = va.z;
            As[0][4 * akq + 3][ar] = va.w;
        }
        *(float4*)&Ws[0][wkr0][4 * wcj0] = vw0;
        *(float4*)&Ws[0][wkr1][4 * wcj1] = vw1;
    }
    __syncthreads();

    float acc[2][4];
#pragma unroll
    for (int j = 0; j < 2; ++j)
#pragma unroll
        for (int c = 0; c < 4; ++c) acc[j][c] = 0.f;

    for (int ch = 0; ch < nch; ++ch) {
        int buf = ch & 1;
        if (ch + 1 < nch) {
            int kb = (c0 + ch + 1) * KC;
            if (t < 256) va = *(const float4*)&A[(size_t)anc * KA + kb + 4 * akq];
            vw0 = *(const float4*)&Wc[(size_t)(kb + wkr0) * NC8 + 4 * wcj0];
            vw1 = *(const float4*)&Wc[(size_t)(kb + wkr1) * NC8 + 4 * wcj1];
        }
#pragma unroll
        for (int kk = 0; kk < KC; ++kk) {
            float4 w = *(const float4*)&Ws[buf][kk][4 * cg];
            float2 a = *(const float2*)&As[buf][kk][2 * ry];
            acc[0][0] += a.x * w.x; acc[0][1] += a.x * w.y;
            acc[0][2] += a.x * w.z; acc[0][3] += a.x * w.w;
            acc[1][0] += a.y * w.x; acc[1][1] += a.y * w.y;
            acc[1][2] += a.y * w.z; acc[1][3] += a.y * w.w;
        }
        if (ch + 1 < nch) {
            int nb = buf ^ 1;
            if (t < 256) {
                As[nb][4 * akq + 0][ar] = va.x;
                As[nb][4 * akq + 1][ar] = va.y;
                As[nb][4 * akq + 2][ar] = va.z;
                As[nb][4 * akq + 3][ar] = va.w;
            }
            *(float4*)&Ws[nb][wkr0][4 * wcj0] = vw0;
            *(float4*)&Ws[nb][wkr1][4 * wcj1] = vw1;
        }
        __syncthreads();
    }

    if (cg < 18) { // cols 4cg..4cg+3 < 72
        int r0 = n0 + 2 * ry;
        float* pb = &P[(size_t)g * NN * CC];
        if (r0 < NN)
            *(float4*)&pb[(size_t)r0 * CC + 4 * cg] =
                make_float4(acc[0][0], acc[0][1], acc[0][2], acc[0][3]);
        if (r0 + 1 < NN)
            *(float4*)&pb[(size_t)(r0 + 1) * CC + 4 * cg] =
                make_float4(acc[1][0], acc[1][1], acc[1][2], acc[1][3]);
    }
}

// ---------------------------------------------------------------- 7b) hout = gelu(P0 + P1)
__global__ void k_gelu(const float* __restrict__ P, float* __restrict__ hout) {
    int i = blockIdx.x * blockDim.x + threadIdx.x;
    if (i < NN * CC) hout[i] = gelu_tanh(P[i] + P[NN * CC + i]);
}

// ---------------------------------------------------------------- 8) out = segpool(h@W_out)/25
__global__ __launch_bounds__(256) void k_out(const float* __restrict__ h,
                                             const float* __restrict__ Wout,
                                             const int* __restrict__ batch,
                                             float* __restrict__ out) {
    __shared__ float sp[NBATCH * OO];
    int tid = threadIdx.x;
    for (int i = tid; i < NBATCH * OO; i += blockDim.x) sp[i] = 0.f;
    __syncthreads();
    int wave = tid >> 6, lane = tid & 63;
    const int WPB = 4;
    for (int n = blockIdx.x * WPB + wave; n < NN; n += gridDim.x * WPB) {
        const float* hr = &h[(size_t)n * CC];
        float acc = 0.f;
#pragma unroll 8
        for (int c = 0; c < CC; ++c) acc += hr[c] * Wout[c * OO + lane];
        atomicAdd(&sp[batch[n] * OO + lane], acc * (1.0f / 25.0f));
    }
    __syncthreads();
    for (int i = tid; i < NBATCH * OO; i += blockDim.x) {
        float v = sp[i];
        if (v != 0.f) atomicAdd(&out[i], v);
    }
}

// ---------------------------------------------------------------- launch
extern "C" void kernel_launch(void* const* d_in, const int* in_sizes, int n_in,
                              void* d_out, int out_size, void* d_ws, size_t ws_size,
                              hipStream_t stream) {
    const float* pos       = (const float*)d_in[0];
    const float* node_attr = (const float*)d_in[1];
    const int*   batch     = (const int*)d_in[2];
    const int*   esrc      = (const int*)d_in[3];
    const int*   edst      = (const int*)d_in[4];
    const float* W_in      = (const float*)d_in[5];
    const float* W_tp      = (const float*)d_in[6];
    const float* W_self    = (const float*)d_in[7];
    const float* W_attr    = (const float*)d_in[8];
    const float* fc1w      = (const float*)d_in[9];
    const float* fc1b      = (const float*)d_in[10];
    const float* fc2w      = (const float*)d_in[11];
    const float* W_out     = (const float*)d_in[12];
    float* out = (float*)d_out;

    char* p = (char*)d_ws;
    auto alloc = [&](size_t bytes) -> void* {
        void* r = (void*)p;
        p += (bytes + 255) & ~(size_t)255;
        return r;
    };
    int*   cnt   = (int*)alloc((size_t)NN * 4);
    int*   cur   = (int*)alloc((size_t)NN * 4);
    int*   off   = (int*)alloc((size_t)(NN + 1) * 4);
    int*   src_s = (int*)alloc((size_t)NE * 4);
    int*   dst_s = (int*)alloc((size_t)NE * 4);
    float* path  = (float*)alloc((size_t)LL * NE * PSTRIDE * 4);
    float* U     = (float*)alloc((size_t)LL * (NB + 1) * 12 * 4);
    float* A     = (float*)alloc((size_t)NN * KA * 4);
    float* Wcat  = (float*)alloc((size_t)LL * KA * NC8 * 4);
    float* P     = (float*)alloc((size_t)2 * NN * CC * 4);
    float* h0    = (float*)alloc((size_t)NN * CC * 4);
    float* h1    = (float*)alloc((size_t)NN * CC * 4);

    hipMemsetAsync(cnt, 0, (size_t)NN * 4, stream);
    hipMemsetAsync(cur, 0, (size_t)NN * 4, stream);
    hipMemsetAsync(out, 0, (size_t)NBATCH * OO * 4, stream);

    k_hist<<<(NE + 255) / 256, 256, 0, stream>>>(pos, esrc, edst, cnt);
    k_utab<<<(LL * (NB + 1) + 255) / 256, 256, 0, stream>>>(fc1w, fc1b, fc2w, U);
    k_wcat<<<(LL * KA * NC8 + 255) / 256, 256, 0, stream>>>(W_tp, W_self, W_attr, Wcat);
    k_init<<<(NN * CC + 255) / 256, 256, 0, stream>>>(W_in, h0);
    k_scan<<<1, 256, 0, stream>>>(cnt, off);
    k_scatter2<<<(NE + 255) / 256, 256, 0, stream>>>(pos, esrc, edst, off, cur, src_s, dst_s);
    k_path2<<<(NE + 255) / 256, 256, 0, stream>>>(pos, src_s, dst_s, U, off, path);

    const float* hin = h0;
    float* hout = h1;
    for (int l = 0; l < LL; ++l) {
        k_z3<<<(NN + 3) / 4, 256, 0, stream>>>(hin, node_attr,
                                               path + (size_t)l * NE * PSTRIDE, src_s, off, A);
        k_agg4<<<dim3((NN + MT - 1) / MT, 2), 320, 0, stream>>>(
            A, Wcat + (size_t)l * KA * NC8, P);
        k_gelu<<<(NN * CC + 255) / 256, 256, 0, stream>>>(P, hout);
        const float* tmp = hin; hin = hout; hout = (float*)tmp;
    }
    k_out<<<128, 256, 0, stream>>>(hin, W_out, batch, out);
}

// Round 7
// 209.384 us; speedup vs baseline: 8.3117x; 1.5179x over previous
//
#include <hip/hip_runtime.h>
#include <math.h>

#define NN 10000     // nodes
#define NE 160000    // edges
#define CC 72        // channels
#define AA 16        // node attr dim
#define LL 3         // layers
#define OO 64        // out dim
#define NBATCH 16
#define SH 9
#define FCN 100
#define KK (SH*CC)   // 648
#define KA 736       // real concat K: 648 Z + 72 h + 16 attr
#define KP 768       // padded K for MFMA (24*32)
#define KG 96        // KP/8 k-groups
#define NT 5         // n-tiles of 16 (80 cols, 72 real)
#define PSTRIDE 12   // padded per-edge path stride (float4-aligned)
#define NB 1024      // u-table bins over t = r/MAX_RADIUS

typedef __attribute__((ext_vector_type(8))) short bf16x8;
typedef __attribute__((ext_vector_type(4))) float f32x4;

// ---------------------------------------------------------------- helpers
static __device__ __forceinline__ float gelu_tanh(float x) {
    float x3 = x * x * x;
    float inner = 0.7978845608028654f * (x + 0.044715f * x3);
    return 0.5f * x * (1.0f + tanhf(inner));
}
static __device__ __forceinline__ unsigned short f2bf(float x) { // RNE
    unsigned int u = __float_as_uint(x);
    u += 0x7FFFu + ((u >> 16) & 1u);
    return (unsigned short)(u >> 16);
}

// ---------------------------------------------------------------- 1) histogram of kept edges per dst
__global__ void k_hist(const float* __restrict__ pos, const int* __restrict__ esrc,
                       const int* __restrict__ edst, int* __restrict__ cnt) {
    int e = blockIdx.x * blockDim.x + threadIdx.x;
    if (e >= NE) return;
    int s = esrc[e], d = edst[e];
    float dx = pos[3 * s] - pos[3 * d];
    float dy = pos[3 * s + 1] - pos[3 * d + 1];
    float dz = pos[3 * s + 2] - pos[3 * d + 2];
    float r = sqrtf(dx * dx + dy * dy + dz * dz);
    // t = r/2 >= 1 -> emb==0 -> silu(0)=0 (fc1_b==0) -> path==0: drop edge.
    if (r * 0.5f < 1.0f) atomicAdd(&cnt[d], 1);
}

// ---------------------------------------------------------------- 2) exclusive scan -> off[0..NN]
__global__ void k_scan(const int* __restrict__ cnt, int* __restrict__ off) {
    __shared__ int sa[256], sb[256];
    const int PER = 40;
    int t = threadIdx.x;
    int base = t * PER;
    int loc[PER];
    int run = 0;
#pragma unroll
    for (int i = 0; i < PER; ++i) {
        int idx = base + i;
        int v = (idx < NN) ? cnt[idx] : 0;
        loc[i] = run;
        run += v;
    }
    sa[t] = run;
    __syncthreads();
    int* in = sa; int* out = sb;
    for (int o = 1; o < 256; o <<= 1) {
        int v = in[t];
        if (t >= o) v += in[t - o];
        out[t] = v;
        __syncthreads();
        int* tmp = in; in = out; out = tmp;
    }
    int ebase = (t > 0) ? in[t - 1] : 0;
#pragma unroll
    for (int i = 0; i < PER; ++i) {
        int idx = base + i;
        if (idx <= NN) off[idx] = ebase + loc[i];
    }
}

// ---------------------------------------------------------------- 3) scatter kept edges dst-sorted
__global__ void k_scatter2(const float* __restrict__ pos, const int* __restrict__ esrc,
                           const int* __restrict__ edst, const int* __restrict__ off,
                           int* __restrict__ cur, int* __restrict__ src_s,
                           int* __restrict__ dst_s) {
    int e = blockIdx.x * blockDim.x + threadIdx.x;
    if (e >= NE) return;
    int s = esrc[e], d = edst[e];
    float dx = pos[3 * s] - pos[3 * d];
    float dy = pos[3 * s + 1] - pos[3 * d + 1];
    float dz = pos[3 * s + 2] - pos[3 * d + 2];
    float r = sqrtf(dx * dx + dy * dy + dz * dz);
    if (r * 0.5f < 1.0f) {
        int slot = off[d] + atomicAdd(&cur[d], 1);
        src_s[slot] = s;
        dst_s[slot] = d;
    }
}

// ---------------------------------------------------------------- 4a) u-table: U[l][b][12], b over t in [0,1]
__global__ void k_utab(const float* __restrict__ fc1w, const float* __restrict__ fc1b,
                       const float* __restrict__ fc2w, float* __restrict__ U) {
    int i = blockIdx.x * blockDim.x + threadIdx.x;
    if (i >= LL * (NB + 1)) return;
    int l = i / (NB + 1), b = i - l * (NB + 1);
    float emb = cosf(1.5707963267948966f * ((float)b / (float)NB));
    float u[SH];
#pragma unroll
    for (int q = 0; q < SH; ++q) u[q] = 0.f;
    const float* w1 = &fc1w[l * FCN];
    const float* b1 = &fc1b[l * FCN];
    const float* w2 = &fc2w[l * FCN * SH];
    for (int f = 0; f < FCN; ++f) {
        float a = emb * w1[f] + b1[f];
        float si = a / (1.0f + expf(-a));
#pragma unroll
        for (int q = 0; q < SH; ++q) u[q] += si * w2[f * SH + q];
    }
    float* ud = &U[(size_t)i * 12];
#pragma unroll
    for (int q = 0; q < SH; ++q) ud[q] = u[q];
    ud[9] = 0.f; ud[10] = 0.f; ud[11] = 0.f;
}

// ---------------------------------------------------------------- 4b) per-edge path via table lerp
__global__ __launch_bounds__(256) void k_path2(const float* __restrict__ pos,
                                               const int* __restrict__ src_s,
                                               const int* __restrict__ dst_s,
                                               const float* __restrict__ U,
                                               const int* __restrict__ off,
                                               float* __restrict__ path) {
    int slot = blockIdx.x * blockDim.x + threadIdx.x;
    if (slot >= off[NN]) return;
    int s = src_s[slot], d = dst_s[slot];
    float dx = pos[3 * s] - pos[3 * d];
    float dy = pos[3 * s + 1] - pos[3 * d + 1];
    float dz = pos[3 * s + 2] - pos[3 * d + 2];
    float r = sqrtf(dx * dx + dy * dy + dz * dz);
    float inv = 1.0f / fmaxf(r, 1e-9f);
    float x = dx * inv, y = dy * inv, z = dz * inv;
    const float s3 = 1.7320508075688772f;
    const float s5 = 2.23606797749979f;
    const float s15 = 3.872983346207417f;
    float sh[SH];
    sh[0] = 1.0f;
    sh[1] = s3 * x;
    sh[2] = s3 * y;
    sh[3] = s3 * z;
    sh[4] = s15 * x * y;
    sh[5] = s15 * y * z;
    sh[6] = 0.5f * s5 * (3.0f * z * z - 1.0f);
    sh[7] = s15 * x * z;
    sh[8] = 0.5f * s15 * (x * x - y * y);

    float fb = r * 0.5f * (float)NB;
    int b0 = (int)fb;
    float fr = fb - (float)b0;

#pragma unroll
    for (int l = 0; l < LL; ++l) {
        const float* t0 = &U[((size_t)l * (NB + 1) + b0) * 12];
        float4 a0 = *(const float4*)(t0 + 0);
        float4 a1 = *(const float4*)(t0 + 4);
        float  a2 = t0[8];
        float4 c0 = *(const float4*)(t0 + 12);
        float4 c1 = *(const float4*)(t0 + 16);
        float  c2 = t0[20];
        float u0 = a0.x + fr * (c0.x - a0.x);
        float u1 = a0.y + fr * (c0.y - a0.y);
        float u2 = a0.z + fr * (c0.z - a0.z);
        float u3 = a0.w + fr * (c0.w - a0.w);
        float u4 = a1.x + fr * (c1.x - a1.x);
        float u5 = a1.y + fr * (c1.y - a1.y);
        float u6 = a1.z + fr * (c1.z - a1.z);
        float u7 = a1.w + fr * (c1.w - a1.w);
        float u8 = a2   + fr * (c2   - a2);
        float* pd = &path[((size_t)l * NE + slot) * PSTRIDE];
        *(float4*)(pd + 0) = make_float4(u0 * sh[0], u1 * sh[1], u2 * sh[2], u3 * sh[3]);
        *(float4*)(pd + 4) = make_float4(u4 * sh[4], u5 * sh[5], u6 * sh[6], u7 * sh[7]);
        *(float4*)(pd + 8) = make_float4(u8 * sh[8], 0.f, 0.f, 0.f);
    }
}

// ---------------------------------------------------------------- 5) h init
__global__ void k_init(const float* __restrict__ W_in, float* __restrict__ h) {
    int i = blockIdx.x * blockDim.x + threadIdx.x;
    if (i < NN * CC) h[i] = W_in[i % CC];
}

// ---------------------------------------------------------------- 5b) Wb[l][nt][kg][16][8] bf16 B-fragment layout
// element (k = kg*8 + e&7, n = nt*16 + e>>3) = [0.25*Wtp ; Wself ; Wattr], zero-padded
__global__ void k_wcat2(const float* __restrict__ Wtp, const float* __restrict__ Wself,
                        const float* __restrict__ Wattr, unsigned short* __restrict__ Wb) {
    int i = blockIdx.x * blockDim.x + threadIdx.x;
    if (i >= LL * NT * KG * 128) return;
    int l = i / (NT * KG * 128);
    int rem = i - l * (NT * KG * 128);
    int nt = rem / (KG * 128); rem -= nt * (KG * 128);
    int kg = rem / 128; int e = rem - kg * 128;
    int n = nt * 16 + (e >> 3);
    int k = kg * 8 + (e & 7);
    float v = 0.f;
    if (n < CC && k < KA) {
        if (k < KK)            v = 0.25f * Wtp[(size_t)l * KK * CC + k * CC + n];
        else if (k < KK + CC)  v = Wself[(size_t)l * CC * CC + (k - KK) * CC + n];
        else                   v = Wattr[(size_t)l * AA * CC + (k - KK - CC) * CC + n];
    }
    Wb[i] = f2bf(v);
}

// ---------------------------------------------------------------- 6) A[d] = [Z(d)|h(d)|attr(d)] bf16, A-fragment tiled
// layout A[row16][kg][16][8]: element (row = r16*16+rr, k = kg*8+kj) at ((r16*KG+kg)*16+rr)*8+kj
__global__ __launch_bounds__(256) void k_z4(const float* __restrict__ h,
                                            const float* __restrict__ attr,
                                            const float* __restrict__ path_l,
                                            const int* __restrict__ src_s,
                                            const int* __restrict__ off,
                                            unsigned short* __restrict__ A) {
    int d = blockIdx.x * 4 + (threadIdx.x >> 6);
    int lane = threadIdx.x & 63;
    if (d >= NN) return;
    float a1[SH], a2[SH];
#pragma unroll
    for (int q = 0; q < SH; ++q) { a1[q] = 0.f; a2[q] = 0.f; }
    int b = off[d], e = off[d + 1];
    bool two = lane < (CC - 64); // lanes 0..7 also handle channel 64+lane
    for (int i = b; i < e; ++i) {
        int s = src_s[i];
        float hv1 = h[(size_t)s * CC + lane];
        float hv2 = two ? h[(size_t)s * CC + 64 + lane] : 0.f;
        const float* p = &path_l[(size_t)i * PSTRIDE];
        float4 p0 = *(const float4*)p;
        float4 p1 = *(const float4*)(p + 4);
        float p8 = p[8];
        a1[0] += p0.x * hv1; a2[0] += p0.x * hv2;
        a1[1] += p0.y * hv1; a2[1] += p0.y * hv2;
        a1[2] += p0.z * hv1; a2[2] += p0.z * hv2;
        a1[3] += p0.w * hv1; a2[3] += p0.w * hv2;
        a1[4] += p1.x * hv1; a2[4] += p1.x * hv2;
        a1[5] += p1.y * hv1; a2[5] += p1.y * hv2;
        a1[6] += p1.z * hv1; a2[6] += p1.z * hv2;
        a1[7] += p1.w * hv1; a2[7] += p1.w * hv2;
        a1[8] += p8 * hv1;   a2[8] += p8 * hv2;
    }
    int rr = d & 15;
    unsigned short* At = A + ((size_t)(d >> 4) * KG) * 128 + rr * 8;
    int kgc = lane >> 3, kjc = lane & 7;
    // Z part: k = q*72 + c  ->  kg = 9q + c/8, kj = c%8
#pragma unroll
    for (int q = 0; q < SH; ++q) {
        At[(9 * q + kgc) * 128 + kjc] = f2bf(a1[q]);
        if (two) At[(9 * q + 8) * 128 + lane] = f2bf(a2[q]); // c2=64+lane: kg=9q+8, kj=lane
    }
    // h part: k = 648 + c -> kg = 81 + c/8
    At[(81 + kgc) * 128 + kjc] = f2bf(h[(size_t)d * CC + lane]);
    if (two) At[89 * 128 + lane] = f2bf(h[(size_t)d * CC + 64 + lane]);
    // attr part: k = 720 + a -> kg = 90 + a/8
    if (lane < AA) At[(90 + (lane >> 3)) * 128 + (lane & 7)] = f2bf(attr[(size_t)d * AA + lane]);
    // zero pad k = 736..767 (kg 92..95)
    if (lane < 32) At[(92 + (lane >> 3)) * 128 + (lane & 7)] = 0;
}

// ---------------------------------------------------------------- 7) hout = gelu(A @ Wb) via MFMA, 4-way K-split in-block
// block = 256 thr = 4 waves; wave w: K-quarter w (6 MFMA k-steps), 16 rows x 80 cols
__global__ __launch_bounds__(256) void k_agg5(const unsigned short* __restrict__ A,
                                              const unsigned short* __restrict__ Wb,
                                              float* __restrict__ hout) {
    __shared__ float red[3 * NT * 64 * 4]; // 15360 B
    int t = threadIdx.x, w = t >> 6, lane = t & 63;
    int r16 = blockIdx.x;
    const unsigned short* Ab = A + (size_t)r16 * KG * 128 + (lane & 15) * 8;
    const unsigned short* Bb = Wb + (lane & 15) * 8;

    f32x4 acc[NT];
#pragma unroll
    for (int nt = 0; nt < NT; ++nt) acc[nt] = (f32x4){0.f, 0.f, 0.f, 0.f};

    int s0 = w * 6;
#pragma unroll
    for (int s = 0; s < 6; ++s) {
        int kg = (s0 + s) * 4 + (lane >> 4);
        bf16x8 af = *(const bf16x8*)(Ab + (size_t)kg * 128);
#pragma unroll
        for (int nt = 0; nt < NT; ++nt) {
            bf16x8 bf = *(const bf16x8*)(Bb + ((size_t)nt * KG + kg) * 128);
            acc[nt] = __builtin_amdgcn_mfma_f32_16x16x32_bf16(af, bf, acc[nt], 0, 0, 0);
        }
    }
    if (w) {
#pragma unroll
        for (int nt = 0; nt < NT; ++nt)
            *(f32x4*)&red[(((w - 1) * NT + nt) * 64 + lane) * 4] = acc[nt];
    }
    __syncthreads();
    if (w == 0) {
        int cb = lane & 15, rb = (lane >> 4) * 4;
        int row = r16 * 16 + rb;
#pragma unroll
        for (int nt = 0; nt < NT; ++nt) {
            f32x4 p0 = *(const f32x4*)&red[((0 * NT + nt) * 64 + lane) * 4];
            f32x4 p1 = *(const f32x4*)&red[((1 * NT + nt) * 64 + lane) * 4];
            f32x4 p2 = *(const f32x4*)&red[((2 * NT + nt) * 64 + lane) * 4];
            int col = nt * 16 + cb;
            if (col < CC) {
#pragma unroll
                for (int j = 0; j < 4; ++j) {
                    float v = acc[nt][j] + p0[j] + p1[j] + p2[j];
                    hout[(size_t)(row + j) * CC + col] = gelu_tanh(v);
                }
            }
        }
    }
}

// ---------------------------------------------------------------- 8) out = segpool(h@W_out)/25
__global__ __launch_bounds__(256) void k_out(const float* __restrict__ h,
                                             const float* __restrict__ Wout,
                                             const int* __restrict__ batch,
                                             float* __restrict__ out) {
    __shared__ float sp[NBATCH * OO];
    int tid = threadIdx.x;
    for (int i = tid; i < NBATCH * OO; i += blockDim.x) sp[i] = 0.f;
    __syncthreads();
    int wave = tid >> 6, lane = tid & 63;
    const int WPB = 4;
    for (int n = blockIdx.x * WPB + wave; n < NN; n += gridDim.x * WPB) {
        const float* hr = &h[(size_t)n * CC];
        float acc = 0.f;
#pragma unroll 8
        for (int c = 0; c < CC; ++c) acc += hr[c] * Wout[c * OO + lane];
        atomicAdd(&sp[batch[n] * OO + lane], acc * (1.0f / 25.0f));
    }
    __syncthreads();
    for (int i = tid; i < NBATCH * OO; i += blockDim.x) {
        float v = sp[i];
        if (v != 0.f) atomicAdd(&out[i], v);
    }
}

// ---------------------------------------------------------------- launch
extern "C" void kernel_launch(void* const* d_in, const int* in_sizes, int n_in,
                              void* d_out, int out_size, void* d_ws, size_t ws_size,
                              hipStream_t stream) {
    const float* pos       = (const float*)d_in[0];
    const float* node_attr = (const float*)d_in[1];
    const int*   batch     = (const int*)d_in[2];
    const int*   esrc      = (const int*)d_in[3];
    const int*   edst      = (const int*)d_in[4];
    const float* W_in      = (const float*)d_in[5];
    const float* W_tp      = (const float*)d_in[6];
    const float* W_self    = (const float*)d_in[7];
    const float* W_attr    = (const float*)d_in[8];
    const float* fc1w      = (const float*)d_in[9];
    const float* fc1b      = (const float*)d_in[10];
    const float* fc2w      = (const float*)d_in[11];
    const float* W_out     = (const float*)d_in[12];
    float* out = (float*)d_out;

    char* p = (char*)d_ws;
    auto alloc = [&](size_t bytes) -> void* {
        void* r = (void*)p;
        p += (bytes + 255) & ~(size_t)255;
        return r;
    };
    int*   cnt   = (int*)alloc((size_t)NN * 4);
    int*   cur   = (int*)alloc((size_t)NN * 4);
    int*   off   = (int*)alloc((size_t)(NN + 1) * 4);
    int*   src_s = (int*)alloc((size_t)NE * 4);
    int*   dst_s = (int*)alloc((size_t)NE * 4);
    float* path  = (float*)alloc((size_t)LL * NE * PSTRIDE * 4);
    float* U     = (float*)alloc((size_t)LL * (NB + 1) * 12 * 4);
    unsigned short* Abf = (unsigned short*)alloc((size_t)(NN / 16) * KG * 128 * 2);
    unsigned short* Wb  = (unsigned short*)alloc((size_t)LL * NT * KG * 128 * 2);
    float* h0    = (float*)alloc((size_t)NN * CC * 4);
    float* h1    = (float*)alloc((size_t)NN * CC * 4);

    hipMemsetAsync(cnt, 0, (size_t)NN * 4, stream);
    hipMemsetAsync(cur, 0, (size_t)NN * 4, stream);
    hipMemsetAsync(out, 0, (size_t)NBATCH * OO * 4, stream);

    k_hist<<<(NE + 255) / 256, 256, 0, stream>>>(pos, esrc, edst, cnt);
    k_utab<<<(LL * (NB + 1) + 255) / 256, 256, 0, stream>>>(fc1w, fc1b, fc2w, U);
    k_wcat2<<<(LL * NT * KG * 128 + 255) / 256, 256, 0, stream>>>(W_tp, W_self, W_attr, Wb);
    k_init<<<(NN * CC + 255) / 256, 256, 0, stream>>>(W_in, h0);
    k_scan<<<1, 256, 0, stream>>>(cnt, off);
    k_scatter2<<<(NE + 255) / 256, 256, 0, stream>>>(pos, esrc, edst, off, cur, src_s, dst_s);
    k_path2<<<(NE + 255) / 256, 256, 0, stream>>>(pos, src_s, dst_s, U, off, path);

    const float* hin = h0;
    float* hout = h1;
    for (int l = 0; l < LL; ++l) {
        k_z4<<<(NN + 3) / 4, 256, 0, stream>>>(hin, node_attr,
                                               path + (size_t)l * NE * PSTRIDE, src_s, off, Abf);
        k_agg5<<<NN / 16, 256, 0, stream>>>(Abf, Wb + (size_t)l * NT * KG * 128, hout);
        const float* tmp = hin; hin = hout; hout = (float*)tmp;
    }
    k_out<<<128, 256, 0, stream>>>(hin, W_out, batch, out);
}

// Round 8
// 173.378 us; speedup vs baseline: 10.0378x; 1.2077x over previous
//
#include <hip/hip_runtime.h>
#include <math.h>

#define NN 10000     // nodes
#define NE 160000    // edges
#define CC 72        // channels
#define AA 16        // node attr dim
#define LL 3         // layers
#define OO 64        // out dim
#define NBATCH 16
#define SH 9
#define FCN 100
#define KK (SH*CC)   // 648
#define KA 736       // real concat K: 648 Z + 72 h + 16 attr
#define KP 768       // padded K for MFMA (24*32)
#define KG 96        // KP/8 k-groups
#define NT 5         // n-tiles of 16 (80 cols, 72 real)
#define PSTRIDE 12   // padded per-edge path stride (float4-aligned)
#define NB 1024      // u-table bins over t = r/MAX_RADIUS

typedef __attribute__((ext_vector_type(8))) short bf16x8;
typedef __attribute__((ext_vector_type(4))) float f32x4;

// ---------------------------------------------------------------- helpers
static __device__ __forceinline__ float gelu_tanh(float x) {
    float x3 = x * x * x;
    float inner = 0.7978845608028654f * (x + 0.044715f * x3);
    return 0.5f * x * (1.0f + tanhf(inner));
}
static __device__ __forceinline__ unsigned short f2bf(float x) { // RNE
    unsigned int u = __float_as_uint(x);
    u += 0x7FFFu + ((u >> 16) & 1u);
    return (unsigned short)(u >> 16);
}

// ---------------------------------------------------------------- 1) histogram of kept edges per dst
__global__ void k_hist(const float* __restrict__ pos, const int* __restrict__ esrc,
                       const int* __restrict__ edst, int* __restrict__ cnt) {
    int e = blockIdx.x * blockDim.x + threadIdx.x;
    if (e >= NE) return;
    int s = esrc[e], d = edst[e];
    float dx = pos[3 * s] - pos[3 * d];
    float dy = pos[3 * s + 1] - pos[3 * d + 1];
    float dz = pos[3 * s + 2] - pos[3 * d + 2];
    float r = sqrtf(dx * dx + dy * dy + dz * dz);
    // t = r/2 >= 1 -> emb==0 -> silu(0)=0 (fc1_b==0) -> path==0: drop edge.
    if (r * 0.5f < 1.0f) atomicAdd(&cnt[d], 1);
}

// ---------------------------------------------------------------- 2) exclusive scan -> off[0..NN]
__global__ void k_scan(const int* __restrict__ cnt, int* __restrict__ off) {
    __shared__ int sa[256], sb[256];
    const int PER = 40;
    int t = threadIdx.x;
    int base = t * PER;
    int loc[PER];
    int run = 0;
#pragma unroll
    for (int i = 0; i < PER; ++i) {
        int idx = base + i;
        int v = (idx < NN) ? cnt[idx] : 0;
        loc[i] = run;
        run += v;
    }
    sa[t] = run;
    __syncthreads();
    int* in = sa; int* out = sb;
    for (int o = 1; o < 256; o <<= 1) {
        int v = in[t];
        if (t >= o) v += in[t - o];
        out[t] = v;
        __syncthreads();
        int* tmp = in; in = out; out = tmp;
    }
    int ebase = (t > 0) ? in[t - 1] : 0;
#pragma unroll
    for (int i = 0; i < PER; ++i) {
        int idx = base + i;
        if (idx <= NN) off[idx] = ebase + loc[i];
    }
}

// ---------------------------------------------------------------- 3) scatter kept edges dst-sorted
__global__ void k_scatter2(const float* __restrict__ pos, const int* __restrict__ esrc,
                           const int* __restrict__ edst, const int* __restrict__ off,
                           int* __restrict__ cur, int* __restrict__ src_s,
                           int* __restrict__ dst_s) {
    int e = blockIdx.x * blockDim.x + threadIdx.x;
    if (e >= NE) return;
    int s = esrc[e], d = edst[e];
    float dx = pos[3 * s] - pos[3 * d];
    float dy = pos[3 * s + 1] - pos[3 * d + 1];
    float dz = pos[3 * s + 2] - pos[3 * d + 2];
    float r = sqrtf(dx * dx + dy * dy + dz * dz);
    if (r * 0.5f < 1.0f) {
        int slot = off[d] + atomicAdd(&cur[d], 1);
        src_s[slot] = s;
        dst_s[slot] = d;
    }
}

// ---------------------------------------------------------------- 4a) u-table: U[l][b][12], b over t in [0,1]
__global__ void k_utab(const float* __restrict__ fc1w, const float* __restrict__ fc1b,
                       const float* __restrict__ fc2w, float* __restrict__ U) {
    int i = blockIdx.x * blockDim.x + threadIdx.x;
    if (i >= LL * (NB + 1)) return;
    int l = i / (NB + 1), b = i - l * (NB + 1);
    float emb = cosf(1.5707963267948966f * ((float)b / (float)NB));
    float u[SH];
#pragma unroll
    for (int q = 0; q < SH; ++q) u[q] = 0.f;
    const float* w1 = &fc1w[l * FCN];
    const float* b1 = &fc1b[l * FCN];
    const float* w2 = &fc2w[l * FCN * SH];
    for (int f = 0; f < FCN; ++f) {
        float a = emb * w1[f] + b1[f];
        float si = a / (1.0f + expf(-a));
#pragma unroll
        for (int q = 0; q < SH; ++q) u[q] += si * w2[f * SH + q];
    }
    float* ud = &U[(size_t)i * 12];
#pragma unroll
    for (int q = 0; q < SH; ++q) ud[q] = u[q];
    ud[9] = 0.f; ud[10] = 0.f; ud[11] = 0.f;
}

// ---------------------------------------------------------------- 4b) per-edge path via table lerp
__global__ __launch_bounds__(256) void k_path2(const float* __restrict__ pos,
                                               const int* __restrict__ src_s,
                                               const int* __restrict__ dst_s,
                                               const float* __restrict__ U,
                                               const int* __restrict__ off,
                                               float* __restrict__ path) {
    int slot = blockIdx.x * blockDim.x + threadIdx.x;
    if (slot >= off[NN]) return;
    int s = src_s[slot], d = dst_s[slot];
    float dx = pos[3 * s] - pos[3 * d];
    float dy = pos[3 * s + 1] - pos[3 * d + 1];
    float dz = pos[3 * s + 2] - pos[3 * d + 2];
    float r = sqrtf(dx * dx + dy * dy + dz * dz);
    float inv = 1.0f / fmaxf(r, 1e-9f);
    float x = dx * inv, y = dy * inv, z = dz * inv;
    const float s3 = 1.7320508075688772f;
    const float s5 = 2.23606797749979f;
    const float s15 = 3.872983346207417f;
    float sh[SH];
    sh[0] = 1.0f;
    sh[1] = s3 * x;
    sh[2] = s3 * y;
    sh[3] = s3 * z;
    sh[4] = s15 * x * y;
    sh[5] = s15 * y * z;
    sh[6] = 0.5f * s5 * (3.0f * z * z - 1.0f);
    sh[7] = s15 * x * z;
    sh[8] = 0.5f * s15 * (x * x - y * y);

    float fb = r * 0.5f * (float)NB;
    int b0 = (int)fb;
    float fr = fb - (float)b0;

#pragma unroll
    for (int l = 0; l < LL; ++l) {
        const float* t0 = &U[((size_t)l * (NB + 1) + b0) * 12];
        float4 a0 = *(const float4*)(t0 + 0);
        float4 a1 = *(const float4*)(t0 + 4);
        float  a2 = t0[8];
        float4 c0 = *(const float4*)(t0 + 12);
        float4 c1 = *(const float4*)(t0 + 16);
        float  c2 = t0[20];
        float u0 = a0.x + fr * (c0.x - a0.x);
        float u1 = a0.y + fr * (c0.y - a0.y);
        float u2 = a0.z + fr * (c0.z - a0.z);
        float u3 = a0.w + fr * (c0.w - a0.w);
        float u4 = a1.x + fr * (c1.x - a1.x);
        float u5 = a1.y + fr * (c1.y - a1.y);
        float u6 = a1.z + fr * (c1.z - a1.z);
        float u7 = a1.w + fr * (c1.w - a1.w);
        float u8 = a2   + fr * (c2   - a2);
        float* pd = &path[((size_t)l * NE + slot) * PSTRIDE];
        *(float4*)(pd + 0) = make_float4(u0 * sh[0], u1 * sh[1], u2 * sh[2], u3 * sh[3]);
        *(float4*)(pd + 4) = make_float4(u4 * sh[4], u5 * sh[5], u6 * sh[6], u7 * sh[7]);
        *(float4*)(pd + 8) = make_float4(u8 * sh[8], 0.f, 0.f, 0.f);
    }
}

// ---------------------------------------------------------------- 5) h init
__global__ void k_init(const float* __restrict__ W_in, float* __restrict__ h) {
    int i = blockIdx.x * blockDim.x + threadIdx.x;
    if (i < NN * CC) h[i] = W_in[i % CC];
}

// ---------------------------------------------------------------- 5b) Wb[l][nt][kg][16][8] bf16 B-fragment layout
__global__ void k_wcat2(const float* __restrict__ Wtp, const float* __restrict__ Wself,
                        const float* __restrict__ Wattr, unsigned short* __restrict__ Wb) {
    int i = blockIdx.x * blockDim.x + threadIdx.x;
    if (i >= LL * NT * KG * 128) return;
    int l = i / (NT * KG * 128);
    int rem = i - l * (NT * KG * 128);
    int nt = rem / (KG * 128); rem -= nt * (KG * 128);
    int kg = rem / 128; int e = rem - kg * 128;
    int n = nt * 16 + (e >> 3);
    int k = kg * 8 + (e & 7);
    float v = 0.f;
    if (n < CC && k < KA) {
        if (k < KK)            v = 0.25f * Wtp[(size_t)l * KK * CC + k * CC + n];
        else if (k < KK + CC)  v = Wself[(size_t)l * CC * CC + (k - KK) * CC + n];
        else                   v = Wattr[(size_t)l * AA * CC + (k - KK - CC) * CC + n];
    }
    Wb[i] = f2bf(v);
}

// ---------------------------------------------------------------- 6) A[d] = [Z(d)|h(d)|attr(d)] bf16, A-fragment tiled
__global__ __launch_bounds__(256) void k_z4(const float* __restrict__ h,
                                            const float* __restrict__ attr,
                                            const float* __restrict__ path_l,
                                            const int* __restrict__ src_s,
                                            const int* __restrict__ off,
                                            unsigned short* __restrict__ A) {
    int d = blockIdx.x * 4 + (threadIdx.x >> 6);
    int lane = threadIdx.x & 63;
    if (d >= NN) return;
    float a1[SH], a2[SH];
#pragma unroll
    for (int q = 0; q < SH; ++q) { a1[q] = 0.f; a2[q] = 0.f; }
    int b = off[d], e = off[d + 1];
    bool two = lane < (CC - 64); // lanes 0..7 also handle channel 64+lane
    for (int i = b; i < e; ++i) {
        int s = src_s[i];
        float hv1 = h[(size_t)s * CC + lane];
        float hv2 = two ? h[(size_t)s * CC + 64 + lane] : 0.f;
        const float* p = &path_l[(size_t)i * PSTRIDE];
        float4 p0 = *(const float4*)p;
        float4 p1 = *(const float4*)(p + 4);
        float p8 = p[8];
        a1[0] += p0.x * hv1; a2[0] += p0.x * hv2;
        a1[1] += p0.y * hv1; a2[1] += p0.y * hv2;
        a1[2] += p0.z * hv1; a2[2] += p0.z * hv2;
        a1[3] += p0.w * hv1; a2[3] += p0.w * hv2;
        a1[4] += p1.x * hv1; a2[4] += p1.x * hv2;
        a1[5] += p1.y * hv1; a2[5] += p1.y * hv2;
        a1[6] += p1.z * hv1; a2[6] += p1.z * hv2;
        a1[7] += p1.w * hv1; a2[7] += p1.w * hv2;
        a1[8] += p8 * hv1;   a2[8] += p8 * hv2;
    }
    int rr = d & 15;
    unsigned short* At = A + ((size_t)(d >> 4) * KG) * 128 + rr * 8;
    int kgc = lane >> 3, kjc = lane & 7;
#pragma unroll
    for (int q = 0; q < SH; ++q) {
        At[(9 * q + kgc) * 128 + kjc] = f2bf(a1[q]);
        if (two) At[(9 * q + 8) * 128 + lane] = f2bf(a2[q]);
    }
    At[(81 + kgc) * 128 + kjc] = f2bf(h[(size_t)d * CC + lane]);
    if (two) At[89 * 128 + lane] = f2bf(h[(size_t)d * CC + 64 + lane]);
    if (lane < AA) At[(90 + (lane >> 3)) * 128 + (lane & 7)] = f2bf(attr[(size_t)d * AA + lane]);
    if (lane < 32) At[(92 + (lane >> 3)) * 128 + (lane & 7)] = 0;
}

// ---------------------------------------------------------------- 7) hout = gelu(A @ Wb) via MFMA, 4-way K-split in-block
__global__ __launch_bounds__(256) void k_agg5(const unsigned short* __restrict__ A,
                                              const unsigned short* __restrict__ Wb,
                                              float* __restrict__ hout) {
    __shared__ float red[3 * NT * 64 * 4]; // 15360 B
    int t = threadIdx.x, w = t >> 6, lane = t & 63;
    int r16 = blockIdx.x;
    const unsigned short* Ab = A + (size_t)r16 * KG * 128 + (lane & 15) * 8;
    const unsigned short* Bb = Wb + (lane & 15) * 8;

    f32x4 acc[NT];
#pragma unroll
    for (int nt = 0; nt < NT; ++nt) acc[nt] = (f32x4){0.f, 0.f, 0.f, 0.f};

    int s0 = w * 6;
#pragma unroll
    for (int s = 0; s < 6; ++s) {
        int kg = (s0 + s) * 4 + (lane >> 4);
        bf16x8 af = *(const bf16x8*)(Ab + (size_t)kg * 128);
#pragma unroll
        for (int nt = 0; nt < NT; ++nt) {
            bf16x8 bf = *(const bf16x8*)(Bb + ((size_t)nt * KG + kg) * 128);
            acc[nt] = __builtin_amdgcn_mfma_f32_16x16x32_bf16(af, bf, acc[nt], 0, 0, 0);
        }
    }
    if (w) {
#pragma unroll
        for (int nt = 0; nt < NT; ++nt)
            *(f32x4*)&red[(((w - 1) * NT + nt) * 64 + lane) * 4] = acc[nt];
    }
    __syncthreads();
    if (w == 0) {
        int cb = lane & 15, rb = (lane >> 4) * 4;
        int row = r16 * 16 + rb;
#pragma unroll
        for (int nt = 0; nt < NT; ++nt) {
            f32x4 p0 = *(const f32x4*)&red[((0 * NT + nt) * 64 + lane) * 4];
            f32x4 p1 = *(const f32x4*)&red[((1 * NT + nt) * 64 + lane) * 4];
            f32x4 p2 = *(const f32x4*)&red[((2 * NT + nt) * 64 + lane) * 4];
            int col = nt * 16 + cb;
            if (col < CC) {
#pragma unroll
                for (int j = 0; j < 4; ++j) {
                    float v = acc[nt][j] + p0[j] + p1[j] + p2[j];
                    hout[(size_t)(row + j) * CC + col] = gelu_tanh(v);
                }
            }
        }
    }
}

// ---------------------------------------------------------------- 8a) hp[b][c] = sum_{n in batch b} h[n][c]  (LDS-privatized)
__global__ __launch_bounds__(256) void k_pool(const float* __restrict__ h,
                                              const int* __restrict__ batch,
                                              float* __restrict__ hp) {
    __shared__ float sp[NBATCH * CC]; // 1152 floats
    int t = threadIdx.x;
    for (int i = t; i < NBATCH * CC; i += 256) sp[i] = 0.f;
    __syncthreads();
    int n0 = blockIdx.x * 16;
    for (int i = t; i < 16 * CC; i += 256) {
        int nl = i / CC, c = i - nl * CC;
        int n = n0 + nl;
        if (n < NN) atomicAdd(&sp[batch[n] * CC + c], h[(size_t)n * CC + c]);
    }
    __syncthreads();
    for (int i = t; i < NBATCH * CC; i += 256) {
        float v = sp[i];
        if (v != 0.f) atomicAdd(&hp[i], v);
    }
}

// ---------------------------------------------------------------- 8b) out = hp @ Wout / 25  (tiny: 16x72 @ 72x64)
__global__ __launch_bounds__(1024) void k_outmm(const float* __restrict__ hp,
                                                const float* __restrict__ Wout,
                                                float* __restrict__ out) {
    __shared__ float hs[NBATCH * CC];
    int t = threadIdx.x;
    for (int i = t; i < NBATCH * CC; i += 1024) hs[i] = hp[i];
    __syncthreads();
    int b = t >> 6, o = t & 63;
    float acc = 0.f;
#pragma unroll 8
    for (int c = 0; c < CC; ++c) acc += hs[b * CC + c] * Wout[c * OO + o];
    out[t] = acc * (1.0f / 25.0f);
}

// ---------------------------------------------------------------- launch
extern "C" void kernel_launch(void* const* d_in, const int* in_sizes, int n_in,
                              void* d_out, int out_size, void* d_ws, size_t ws_size,
                              hipStream_t stream) {
    const float* pos       = (const float*)d_in[0];
    const float* node_attr = (const float*)d_in[1];
    const int*   batch     = (const int*)d_in[2];
    const int*   esrc      = (const int*)d_in[3];
    const int*   edst      = (const int*)d_in[4];
    const float* W_in      = (const float*)d_in[5];
    const float* W_tp      = (const float*)d_in[6];
    const float* W_self    = (const float*)d_in[7];
    const float* W_attr    = (const float*)d_in[8];
    const float* fc1w      = (const float*)d_in[9];
    const float* fc1b      = (const float*)d_in[10];
    const float* fc2w      = (const float*)d_in[11];
    const float* W_out     = (const float*)d_in[12];
    float* out = (float*)d_out;

    char* p = (char*)d_ws;
    auto alloc = [&](size_t bytes) -> void* {
        void* r = (void*)p;
        p += (bytes + 255) & ~(size_t)255;
        return r;
    };
    int*   cnt   = (int*)alloc((size_t)NN * 4);
    int*   cur   = (int*)alloc((size_t)NN * 4);
    int*   off   = (int*)alloc((size_t)(NN + 1) * 4);
    int*   src_s = (int*)alloc((size_t)NE * 4);
    int*   dst_s = (int*)alloc((size_t)NE * 4);
    float* path  = (float*)alloc((size_t)LL * NE * PSTRIDE * 4);
    float* U     = (float*)alloc((size_t)LL * (NB + 1) * 12 * 4);
    unsigned short* Abf = (unsigned short*)alloc((size_t)(NN / 16) * KG * 128 * 2);
    unsigned short* Wb  = (unsigned short*)alloc((size_t)LL * NT * KG * 128 * 2);
    float* h0    = (float*)alloc((size_t)NN * CC * 4);
    float* h1    = (float*)alloc((size_t)NN * CC * 4);
    float* hp    = (float*)alloc((size_t)NBATCH * CC * 4);

    hipMemsetAsync(cnt, 0, (size_t)NN * 4, stream);
    hipMemsetAsync(cur, 0, (size_t)NN * 4, stream);
    hipMemsetAsync(hp, 0, (size_t)NBATCH * CC * 4, stream);

    k_hist<<<(NE + 255) / 256, 256, 0, stream>>>(pos, esrc, edst, cnt);
    k_utab<<<(LL * (NB + 1) + 255) / 256, 256, 0, stream>>>(fc1w, fc1b, fc2w, U);
    k_wcat2<<<(LL * NT * KG * 128 + 255) / 256, 256, 0, stream>>>(W_tp, W_self, W_attr, Wb);
    k_init<<<(NN * CC + 255) / 256, 256, 0, stream>>>(W_in, h0);
    k_scan<<<1, 256, 0, stream>>>(cnt, off);
    k_scatter2<<<(NE + 255) / 256, 256, 0, stream>>>(pos, esrc, edst, off, cur, src_s, dst_s);
    k_path2<<<(NE + 255) / 256, 256, 0, stream>>>(pos, src_s, dst_s, U, off, path);

    const float* hin = h0;
    float* hout = h1;
    for (int l = 0; l < LL; ++l) {
        k_z4<<<(NN + 3) / 4, 256, 0, stream>>>(hin, node_attr,
                                               path + (size_t)l * NE * PSTRIDE, src_s, off, Abf);
        k_agg5<<<NN / 16, 256, 0, stream>>>(Abf, Wb + (size_t)l * NT * KG * 128, hout);
        const float* tmp = hin; hin = hout; hout = (float*)tmp;
    }
    k_pool<<<(NN + 15) / 16, 256, 0, stream>>>(hin, batch, hp);
    k_outmm<<<1, 1024, 0, stream>>>(hp, W_out, out);
}

// Round 9
// 166.013 us; speedup vs baseline: 10.4831x; 1.0444x over previous
//
#include <hip/hip_runtime.h>
#include <math.h>

#define NN 10000     // nodes
#define NE 160000    // edges
#define CC 72        // channels
#define AA 16        // node attr dim
#define LL 3         // layers
#define OO 64        // out dim
#define NBATCH 16
#define SH 9
#define FCN 100
#define KK (SH*CC)   // 648
#define KA 736       // real concat K: 648 Z + 72 h + 16 attr
#define KP 768       // padded K for MFMA (24*32)
#define KG 96        // KP/8 k-groups
#define NT 5         // n-tiles of 16 (80 cols, 72 real)
#define PSTRIDE 12   // padded per-edge path stride (float4-aligned)
#define NB 1024      // u-table bins over t = r/MAX_RADIUS

typedef __attribute__((ext_vector_type(8))) short bf16x8;
typedef __attribute__((ext_vector_type(4))) float f32x4;

// ---------------------------------------------------------------- helpers
static __device__ __forceinline__ float gelu_tanh(float x) {
    float x3 = x * x * x;
    float inner = 0.7978845608028654f * (x + 0.044715f * x3);
    return 0.5f * x * (1.0f + tanhf(inner));
}
static __device__ __forceinline__ unsigned short f2bf(float x) { // RNE
    unsigned int u = __float_as_uint(x);
    u += 0x7FFFu + ((u >> 16) & 1u);
    return (unsigned short)(u >> 16);
}

// ---------------------------------------------------------------- 1) histogram of kept edges per dst
__global__ void k_hist(const float* __restrict__ pos, const int* __restrict__ esrc,
                       const int* __restrict__ edst, int* __restrict__ cnt) {
    int e = blockIdx.x * blockDim.x + threadIdx.x;
    if (e >= NE) return;
    int s = esrc[e], d = edst[e];
    float dx = pos[3 * s] - pos[3 * d];
    float dy = pos[3 * s + 1] - pos[3 * d + 1];
    float dz = pos[3 * s + 2] - pos[3 * d + 2];
    float r = sqrtf(dx * dx + dy * dy + dz * dz);
    // t = r/2 >= 1 -> emb==0 -> silu(0)=0 (fc1_b==0) -> path==0: drop edge.
    if (r * 0.5f < 1.0f) atomicAdd(&cnt[d], 1);
}

// ---------------------------------------------------------------- 2) exclusive scan -> off[0..NN]
__global__ void k_scan(const int* __restrict__ cnt, int* __restrict__ off) {
    __shared__ int sa[256], sb[256];
    const int PER = 40;
    int t = threadIdx.x;
    int base = t * PER;
    int loc[PER];
    int run = 0;
#pragma unroll
    for (int i = 0; i < PER; ++i) {
        int idx = base + i;
        int v = (idx < NN) ? cnt[idx] : 0;
        loc[i] = run;
        run += v;
    }
    sa[t] = run;
    __syncthreads();
    int* in = sa; int* out = sb;
    for (int o = 1; o < 256; o <<= 1) {
        int v = in[t];
        if (t >= o) v += in[t - o];
        out[t] = v;
        __syncthreads();
        int* tmp = in; in = out; out = tmp;
    }
    int ebase = (t > 0) ? in[t - 1] : 0;
#pragma unroll
    for (int i = 0; i < PER; ++i) {
        int idx = base + i;
        if (idx <= NN) off[idx] = ebase + loc[i];
    }
}

// ---------------------------------------------------------------- 3) scatter kept edges dst-sorted
__global__ void k_scatter2(const float* __restrict__ pos, const int* __restrict__ esrc,
                           const int* __restrict__ edst, const int* __restrict__ off,
                           int* __restrict__ cur, int* __restrict__ src_s,
                           int* __restrict__ dst_s) {
    int e = blockIdx.x * blockDim.x + threadIdx.x;
    if (e >= NE) return;
    int s = esrc[e], d = edst[e];
    float dx = pos[3 * s] - pos[3 * d];
    float dy = pos[3 * s + 1] - pos[3 * d + 1];
    float dz = pos[3 * s + 2] - pos[3 * d + 2];
    float r = sqrtf(dx * dx + dy * dy + dz * dz);
    if (r * 0.5f < 1.0f) {
        int slot = off[d] + atomicAdd(&cur[d], 1);
        src_s[slot] = s;
        dst_s[slot] = d;
    }
}

// ---------------------------------------------------------------- 4a) u-table: U[l][b][12], b over t in [0,1]
__global__ void k_utab(const float* __restrict__ fc1w, const float* __restrict__ fc1b,
                       const float* __restrict__ fc2w, float* __restrict__ U) {
    int i = blockIdx.x * blockDim.x + threadIdx.x;
    if (i >= LL * (NB + 1)) return;
    int l = i / (NB + 1), b = i - l * (NB + 1);
    float emb = cosf(1.5707963267948966f * ((float)b / (float)NB));
    float u[SH];
#pragma unroll
    for (int q = 0; q < SH; ++q) u[q] = 0.f;
    const float* w1 = &fc1w[l * FCN];
    const float* b1 = &fc1b[l * FCN];
    const float* w2 = &fc2w[l * FCN * SH];
    for (int f = 0; f < FCN; ++f) {
        float a = emb * w1[f] + b1[f];
        float si = a / (1.0f + expf(-a));
#pragma unroll
        for (int q = 0; q < SH; ++q) u[q] += si * w2[f * SH + q];
    }
    float* ud = &U[(size_t)i * 12];
#pragma unroll
    for (int q = 0; q < SH; ++q) ud[q] = u[q];
    ud[9] = 0.f; ud[10] = 0.f; ud[11] = 0.f;
}

// ---------------------------------------------------------------- 4b) per-edge path via table lerp
__global__ __launch_bounds__(256) void k_path2(const float* __restrict__ pos,
                                               const int* __restrict__ src_s,
                                               const int* __restrict__ dst_s,
                                               const float* __restrict__ U,
                                               const int* __restrict__ off,
                                               float* __restrict__ path) {
    int slot = blockIdx.x * blockDim.x + threadIdx.x;
    if (slot >= off[NN]) return;
    int s = src_s[slot], d = dst_s[slot];
    float dx = pos[3 * s] - pos[3 * d];
    float dy = pos[3 * s + 1] - pos[3 * d + 1];
    float dz = pos[3 * s + 2] - pos[3 * d + 2];
    float r = sqrtf(dx * dx + dy * dy + dz * dz);
    float inv = 1.0f / fmaxf(r, 1e-9f);
    float x = dx * inv, y = dy * inv, z = dz * inv;
    const float s3 = 1.7320508075688772f;
    const float s5 = 2.23606797749979f;
    const float s15 = 3.872983346207417f;
    float sh[SH];
    sh[0] = 1.0f;
    sh[1] = s3 * x;
    sh[2] = s3 * y;
    sh[3] = s3 * z;
    sh[4] = s15 * x * y;
    sh[5] = s15 * y * z;
    sh[6] = 0.5f * s5 * (3.0f * z * z - 1.0f);
    sh[7] = s15 * x * z;
    sh[8] = 0.5f * s15 * (x * x - y * y);

    float fb = r * 0.5f * (float)NB;
    int b0 = (int)fb;
    float fr = fb - (float)b0;

#pragma unroll
    for (int l = 0; l < LL; ++l) {
        const float* t0 = &U[((size_t)l * (NB + 1) + b0) * 12];
        float4 a0 = *(const float4*)(t0 + 0);
        float4 a1 = *(const float4*)(t0 + 4);
        float  a2 = t0[8];
        float4 c0 = *(const float4*)(t0 + 12);
        float4 c1 = *(const float4*)(t0 + 16);
        float  c2 = t0[20];
        float u0 = a0.x + fr * (c0.x - a0.x);
        float u1 = a0.y + fr * (c0.y - a0.y);
        float u2 = a0.z + fr * (c0.z - a0.z);
        float u3 = a0.w + fr * (c0.w - a0.w);
        float u4 = a1.x + fr * (c1.x - a1.x);
        float u5 = a1.y + fr * (c1.y - a1.y);
        float u6 = a1.z + fr * (c1.z - a1.z);
        float u7 = a1.w + fr * (c1.w - a1.w);
        float u8 = a2   + fr * (c2   - a2);
        float* pd = &path[((size_t)l * NE + slot) * PSTRIDE];
        *(float4*)(pd + 0) = make_float4(u0 * sh[0], u1 * sh[1], u2 * sh[2], u3 * sh[3]);
        *(float4*)(pd + 4) = make_float4(u4 * sh[4], u5 * sh[5], u6 * sh[6], u7 * sh[7]);
        *(float4*)(pd + 8) = make_float4(u8 * sh[8], 0.f, 0.f, 0.f);
    }
}

// ---------------------------------------------------------------- 5) h init
__global__ void k_init(const float* __restrict__ W_in, float* __restrict__ h) {
    int i = blockIdx.x * blockDim.x + threadIdx.x;
    if (i < NN * CC) h[i] = W_in[i % CC];
}

// ---------------------------------------------------------------- 5b) Wb[l][nt][kg][16][8] bf16 B-fragment layout
__global__ void k_wcat2(const float* __restrict__ Wtp, const float* __restrict__ Wself,
                        const float* __restrict__ Wattr, unsigned short* __restrict__ Wb) {
    int i = blockIdx.x * blockDim.x + threadIdx.x;
    if (i >= LL * NT * KG * 128) return;
    int l = i / (NT * KG * 128);
    int rem = i - l * (NT * KG * 128);
    int nt = rem / (KG * 128); rem -= nt * (KG * 128);
    int kg = rem / 128; int e = rem - kg * 128;
    int n = nt * 16 + (e >> 3);
    int k = kg * 8 + (e & 7);
    float v = 0.f;
    if (n < CC && k < KA) {
        if (k < KK)            v = 0.25f * Wtp[(size_t)l * KK * CC + k * CC + n];
        else if (k < KK + CC)  v = Wself[(size_t)l * CC * CC + (k - KK) * CC + n];
        else                   v = Wattr[(size_t)l * AA * CC + (k - KK - CC) * CC + n];
    }
    Wb[i] = f2bf(v);
}

// ---------------------------------------------------------------- 6) fused layer: Z-gather -> LDS bf16 fragments -> MFMA -> gelu
// 625 blocks x 1024 threads (16 waves). Wave w owns node d = blk*16 + w.
// Phase 1: per-node Z/h/attr accumulation, fragments staged in LDS.
// Phase 2: waves 0-3 do the 4-way K-split MFMA GEMM; wave 0 reduces + gelu.
__global__ __launch_bounds__(1024) void k_layer(const float* __restrict__ h,
                                                const float* __restrict__ attr,
                                                const float* __restrict__ path_l,
                                                const int* __restrict__ src_s,
                                                const int* __restrict__ off,
                                                const unsigned short* __restrict__ Wb,
                                                float* __restrict__ hout) {
    __shared__ unsigned short Alds[KG * 128]; // 24576 B, [kg][row16][kj]
    __shared__ float red[3 * NT * 64 * 4];    // 15360 B
    int t = threadIdx.x, w = t >> 6, lane = t & 63;
    int n0 = blockIdx.x * 16;
    int d = n0 + w; // NN == 625*16: always in range

    // ---- phase 1: Z accumulation for node d (identical math to old k_z4)
    float a1[SH], a2[SH];
#pragma unroll
    for (int q = 0; q < SH; ++q) { a1[q] = 0.f; a2[q] = 0.f; }
    int b = off[d], e = off[d + 1];
    bool two = lane < (CC - 64); // lanes 0..7 also own channel 64+lane
    for (int i = b; i < e; ++i) {
        int s = src_s[i];
        float hv1 = h[(size_t)s * CC + lane];
        float hv2 = two ? h[(size_t)s * CC + 64 + lane] : 0.f;
        const float* p = &path_l[(size_t)i * PSTRIDE];
        float4 p0 = *(const float4*)p;
        float4 p1 = *(const float4*)(p + 4);
        float p8 = p[8];
        a1[0] += p0.x * hv1; a2[0] += p0.x * hv2;
        a1[1] += p0.y * hv1; a2[1] += p0.y * hv2;
        a1[2] += p0.z * hv1; a2[2] += p0.z * hv2;
        a1[3] += p0.w * hv1; a2[3] += p0.w * hv2;
        a1[4] += p1.x * hv1; a2[4] += p1.x * hv2;
        a1[5] += p1.y * hv1; a2[5] += p1.y * hv2;
        a1[6] += p1.z * hv1; a2[6] += p1.z * hv2;
        a1[7] += p1.w * hv1; a2[7] += p1.w * hv2;
        a1[8] += p8 * hv1;   a2[8] += p8 * hv2;
    }
    // stage fragments: element (row=w, k=kg*8+kj) at Alds[kg*128 + w*8 + kj]
    unsigned short* At = Alds + w * 8;
    int kgc = lane >> 3, kjc = lane & 7;
#pragma unroll
    for (int q = 0; q < SH; ++q) {
        At[(9 * q + kgc) * 128 + kjc] = f2bf(a1[q]);
        if (two) At[(9 * q + 8) * 128 + lane] = f2bf(a2[q]); // c=64+lane: kj=lane
    }
    At[(81 + kgc) * 128 + kjc] = f2bf(h[(size_t)d * CC + lane]);
    if (two) At[89 * 128 + lane] = f2bf(h[(size_t)d * CC + 64 + lane]);
    if (lane < AA) At[(90 + (lane >> 3)) * 128 + (lane & 7)] = f2bf(attr[(size_t)d * AA + lane]);
    if (lane < 32) At[(92 + (lane >> 3)) * 128 + (lane & 7)] = 0;
    __syncthreads();

    // ---- phase 2: GEMM (waves 0-3), K-quarter per wave
    if (w < 4) {
        const unsigned short* Ab = Alds + (lane & 15) * 8;
        const unsigned short* Bb = Wb + (lane & 15) * 8;
        f32x4 acc[NT];
#pragma unroll
        for (int nt = 0; nt < NT; ++nt) acc[nt] = (f32x4){0.f, 0.f, 0.f, 0.f};
        int s0 = w * 6;
#pragma unroll
        for (int s = 0; s < 6; ++s) {
            int kg = (s0 + s) * 4 + (lane >> 4);
            bf16x8 af = *(const bf16x8*)(Ab + (size_t)kg * 128);
#pragma unroll
            for (int nt = 0; nt < NT; ++nt) {
                bf16x8 bf = *(const bf16x8*)(Bb + ((size_t)nt * KG + kg) * 128);
                acc[nt] = __builtin_amdgcn_mfma_f32_16x16x32_bf16(af, bf, acc[nt], 0, 0, 0);
            }
        }
        if (w) {
#pragma unroll
            for (int nt = 0; nt < NT; ++nt)
                *(f32x4*)&red[(((w - 1) * NT + nt) * 64 + lane) * 4] = acc[nt];
        }
        __syncthreads();
        if (w == 0) {
            int cb = lane & 15, rb = (lane >> 4) * 4;
            int row = n0 + rb;
#pragma unroll
            for (int nt = 0; nt < NT; ++nt) {
                f32x4 p0 = *(const f32x4*)&red[((0 * NT + nt) * 64 + lane) * 4];
                f32x4 p1 = *(const f32x4*)&red[((1 * NT + nt) * 64 + lane) * 4];
                f32x4 p2 = *(const f32x4*)&red[((2 * NT + nt) * 64 + lane) * 4];
                int col = nt * 16 + cb;
                if (col < CC) {
#pragma unroll
                    for (int j = 0; j < 4; ++j) {
                        float v = acc[nt][j] + p0[j] + p1[j] + p2[j];
                        hout[(size_t)(row + j) * CC + col] = gelu_tanh(v);
                    }
                }
            }
        }
    } else {
        __syncthreads(); // match phase-2 barrier
    }
}

// ---------------------------------------------------------------- 8a) hp[b][c] = sum_{n in batch b} h[n][c]  (LDS-privatized)
__global__ __launch_bounds__(256) void k_pool(const float* __restrict__ h,
                                              const int* __restrict__ batch,
                                              float* __restrict__ hp) {
    __shared__ float sp[NBATCH * CC]; // 1152 floats
    int t = threadIdx.x;
    for (int i = t; i < NBATCH * CC; i += 256) sp[i] = 0.f;
    __syncthreads();
    int n0 = blockIdx.x * 16;
    for (int i = t; i < 16 * CC; i += 256) {
        int nl = i / CC, c = i - nl * CC;
        int n = n0 + nl;
        if (n < NN) atomicAdd(&sp[batch[n] * CC + c], h[(size_t)n * CC + c]);
    }
    __syncthreads();
    for (int i = t; i < NBATCH * CC; i += 256) {
        float v = sp[i];
        if (v != 0.f) atomicAdd(&hp[i], v);
    }
}

// ---------------------------------------------------------------- 8b) out = hp @ Wout / 25  (tiny: 16x72 @ 72x64)
__global__ __launch_bounds__(1024) void k_outmm(const float* __restrict__ hp,
                                                const float* __restrict__ Wout,
                                                float* __restrict__ out) {
    __shared__ float hs[NBATCH * CC];
    int t = threadIdx.x;
    for (int i = t; i < NBATCH * CC; i += 1024) hs[i] = hp[i];
    __syncthreads();
    int b = t >> 6, o = t & 63;
    float acc = 0.f;
#pragma unroll 8
    for (int c = 0; c < CC; ++c) acc += hs[b * CC + c] * Wout[c * OO + o];
    out[t] = acc * (1.0f / 25.0f);
}

// ---------------------------------------------------------------- launch
extern "C" void kernel_launch(void* const* d_in, const int* in_sizes, int n_in,
                              void* d_out, int out_size, void* d_ws, size_t ws_size,
                              hipStream_t stream) {
    const float* pos       = (const float*)d_in[0];
    const float* node_attr = (const float*)d_in[1];
    const int*   batch     = (const int*)d_in[2];
    const int*   esrc      = (const int*)d_in[3];
    const int*   edst      = (const int*)d_in[4];
    const float* W_in      = (const float*)d_in[5];
    const float* W_tp      = (const float*)d_in[6];
    const float* W_self    = (const float*)d_in[7];
    const float* W_attr    = (const float*)d_in[8];
    const float* fc1w      = (const float*)d_in[9];
    const float* fc1b      = (const float*)d_in[10];
    const float* fc2w      = (const float*)d_in[11];
    const float* W_out     = (const float*)d_in[12];
    float* out = (float*)d_out;

    char* p = (char*)d_ws;
    auto alloc = [&](size_t bytes) -> void* {
        void* r = (void*)p;
        p += (bytes + 255) & ~(size_t)255;
        return r;
    };
    int*   cnt   = (int*)alloc((size_t)NN * 4);
    int*   cur   = (int*)alloc((size_t)NN * 4);
    int*   off   = (int*)alloc((size_t)(NN + 1) * 4);
    int*   src_s = (int*)alloc((size_t)NE * 4);
    int*   dst_s = (int*)alloc((size_t)NE * 4);
    float* path  = (float*)alloc((size_t)LL * NE * PSTRIDE * 4);
    float* U     = (float*)alloc((size_t)LL * (NB + 1) * 12 * 4);
    unsigned short* Wb = (unsigned short*)alloc((size_t)LL * NT * KG * 128 * 2);
    float* h0    = (float*)alloc((size_t)NN * CC * 4);
    float* h1    = (float*)alloc((size_t)NN * CC * 4);
    float* hp    = (float*)alloc((size_t)NBATCH * CC * 4);

    hipMemsetAsync(cnt, 0, (size_t)NN * 4, stream);
    hipMemsetAsync(cur, 0, (size_t)NN * 4, stream);
    hipMemsetAsync(hp, 0, (size_t)NBATCH * CC * 4, stream);

    k_hist<<<(NE + 255) / 256, 256, 0, stream>>>(pos, esrc, edst, cnt);
    k_utab<<<(LL * (NB + 1) + 255) / 256, 256, 0, stream>>>(fc1w, fc1b, fc2w, U);
    k_wcat2<<<(LL * NT * KG * 128 + 255) / 256, 256, 0, stream>>>(W_tp, W_self, W_attr, Wb);
    k_init<<<(NN * CC + 255) / 256, 256, 0, stream>>>(W_in, h0);
    k_scan<<<1, 256, 0, stream>>>(cnt, off);
    k_scatter2<<<(NE + 255) / 256, 256, 0, stream>>>(pos, esrc, edst, off, cur, src_s, dst_s);
    k_path2<<<(NE + 255) / 256, 256, 0, stream>>>(pos, src_s, dst_s, U, off, path);

    const float* hin = h0;
    float* hout = h1;
    for (int l = 0; l < LL; ++l) {
        k_layer<<<NN / 16, 1024, 0, stream>>>(hin, node_attr,
                                              path + (size_t)l * NE * PSTRIDE, src_s, off,
                                              Wb + (size_t)l * NT * KG * 128, hout);
        const float* tmp = hin; hin = hout; hout = (float*)tmp;
    }
    k_pool<<<(NN + 15) / 16, 256, 0, stream>>>(hin, batch, hp);
    k_outmm<<<1, 1024, 0, stream>>>(hp, W_out, out);
}